// Round 10
// baseline (242.711 us; speedup 1.0000x reference)
//
#include <hip/hip_runtime.h>

#define NN 100000      // nodes
#define DD 128         // embedding dim
#define KE 300         // raw feature dim
#define NE 1600000     // edges
#define NB 4096        // batch (users)
#define HL 50          // history length
#define CL 20          // candidates

#define NBUCK 1563     // ceil(NN/64): buckets of 64 dst nodes
#define SLOT  1280     // max edges/bucket (mean 1024, sigma 32, +8 sigma)
#define PBLK  250      // partition blocks
#define EPB   6400     // edges per partition block
#define EPT   25       // edges per thread

#define WTE_N 40960    // 128 cols x 320 k, fragment-major
#define WTG_N 16384    // 128 cols x 128 k, fragment-major

typedef unsigned short ushort_t;
using bf16x8 = __attribute__((ext_vector_type(8))) short;
using f32x4  = __attribute__((ext_vector_type(4))) float;

union U4B { uint4 u; bf16x8 b; unsigned a[4]; };

__device__ __forceinline__ ushort_t f2bf(float f) {
    unsigned u = __float_as_uint(f);
    unsigned r = u + 0x7FFF + ((u >> 16) & 1);   // RNE
    return (ushort_t)(r >> 16);
}
__device__ __forceinline__ float bf2f(unsigned s) {
    return __uint_as_float(s << 16);
}
__device__ __forceinline__ bf16x8 pack8(float4 a, float4 b) {
    U4B r;
    r.a[0] = (unsigned)f2bf(a.x) | ((unsigned)f2bf(a.y) << 16);
    r.a[1] = (unsigned)f2bf(a.z) | ((unsigned)f2bf(a.w) << 16);
    r.a[2] = (unsigned)f2bf(b.x) | ((unsigned)f2bf(b.y) << 16);
    r.a[3] = (unsigned)f2bf(b.z) | ((unsigned)f2bf(b.w) << 16);
    return r.b;
}

// ------- weight prep: fragment-major bf16 layouts for barrier-free GEMMs ----
// wtF[((chunk*8+cf)*64 + lane)*8 + j] = W[k][n],
//   k = chunk*32 + (lane>>4)*8 + j,  n = cf*16 + (lane&15).
__global__ __launch_bounds__(256) void prep_w(const float* __restrict__ We,
                                              const float* __restrict__ Wg,
                                              ushort_t* __restrict__ wte,
                                              ushort_t* __restrict__ wtg) {
    int i = blockIdx.x * 256 + threadIdx.x;
    if (i < WTE_N) {
        int j = i & 7, lane = (i >> 3) & 63, cf = (i >> 9) & 7, ch = i >> 12;
        int k = ch * 32 + (lane >> 4) * 8 + j;
        int n = cf * 16 + (lane & 15);
        wte[i] = f2bf((k < KE) ? We[k * DD + n] : 0.f);
    } else if (i < WTE_N + WTG_N) {
        int t = i - WTE_N;
        int j = t & 7, lane = (t >> 3) & 63, cf = (t >> 9) & 7, ks = t >> 12;
        int k = ks * 32 + (lane >> 4) * 8 + j;
        int n = cf * 16 + (lane & 15);
        wtg[t] = f2bf(Wg[k * DD + n]);
    }
}

// ---- masked A fragment loader (tail chunk only) ----------------------------
__device__ __forceinline__ bf16x8 loadA8m(const float* __restrict__ x,
                                          int row, int col, bool rowok) {
    float v[8];
#pragma unroll
    for (int j = 0; j < 8; ++j) {
        int c = col + j;
        v[j] = (rowok && c < KE) ? x[(long long)row * KE + c] : 0.f;
    }
    return pack8(make_float4(v[0], v[1], v[2], v[3]),
                 make_float4(v[4], v[5], v[6], v[7]));
}

#define MFMA16(A0, A1)                                                          \
    do {                                                                        \
        acc0[0] = __builtin_amdgcn_mfma_f32_16x16x32_bf16(A0, b0, acc0[0], 0, 0, 0); \
        acc1[0] = __builtin_amdgcn_mfma_f32_16x16x32_bf16(A1, b0, acc1[0], 0, 0, 0); \
        acc0[1] = __builtin_amdgcn_mfma_f32_16x16x32_bf16(A0, b1, acc0[1], 0, 0, 0); \
        acc1[1] = __builtin_amdgcn_mfma_f32_16x16x32_bf16(A1, b1, acc1[1], 0, 0, 0); \
        acc0[2] = __builtin_amdgcn_mfma_f32_16x16x32_bf16(A0, b2, acc0[2], 0, 0, 0); \
        acc1[2] = __builtin_amdgcn_mfma_f32_16x16x32_bf16(A1, b2, acc1[2], 0, 0, 0); \
        acc0[3] = __builtin_amdgcn_mfma_f32_16x16x32_bf16(A0, b3, acc0[3], 0, 0, 0); \
        acc1[3] = __builtin_amdgcn_mfma_f32_16x16x32_bf16(A1, b3, acc1[3], 0, 0, 0); \
        acc0[4] = __builtin_amdgcn_mfma_f32_16x16x32_bf16(A0, b4, acc0[4], 0, 0, 0); \
        acc1[4] = __builtin_amdgcn_mfma_f32_16x16x32_bf16(A1, b4, acc1[4], 0, 0, 0); \
        acc0[5] = __builtin_amdgcn_mfma_f32_16x16x32_bf16(A0, b5, acc0[5], 0, 0, 0); \
        acc1[5] = __builtin_amdgcn_mfma_f32_16x16x32_bf16(A1, b5, acc1[5], 0, 0, 0); \
        acc0[6] = __builtin_amdgcn_mfma_f32_16x16x32_bf16(A0, b6, acc0[6], 0, 0, 0); \
        acc1[6] = __builtin_amdgcn_mfma_f32_16x16x32_bf16(A1, b6, acc1[6], 0, 0, 0); \
        acc0[7] = __builtin_amdgcn_mfma_f32_16x16x32_bf16(A0, b7, acc0[7], 0, 0, 0); \
        acc1[7] = __builtin_amdgcn_mfma_f32_16x16x32_bf16(A1, b7, acc1[7], 0, 0, 0); \
    } while (0)

#define LOADB(c)                                                                \
    const ushort_t* bp = &wtF[(c) * 8 * 512 + lane * 8];                        \
    bf16x8 b0 = *(const bf16x8*)&bp[0 * 512];                                   \
    bf16x8 b1 = *(const bf16x8*)&bp[1 * 512];                                   \
    bf16x8 b2 = *(const bf16x8*)&bp[2 * 512];                                   \
    bf16x8 b3 = *(const bf16x8*)&bp[3 * 512];                                   \
    bf16x8 b4 = *(const bf16x8*)&bp[4 * 512];                                   \
    bf16x8 b5 = *(const bf16x8*)&bp[5 * 512];                                   \
    bf16x8 b6 = *(const bf16x8*)&bp[6 * 512];                                   \
    bf16x8 b7 = *(const bf16x8*)&bp[7 * 512]

// ---------------- encoder: news_bf = bf16( x @ Wenc ) -----------------------
// 32 rows/wave (2 row-frags): 64 acc VGPRs force B-fragment liveness, each
// B frag feeds 2 MFMAs. Depth-1 A prefetch. No LDS, no barriers.
__global__ __launch_bounds__(256) void enc_mfma(const float* __restrict__ x,
                                                const ushort_t* __restrict__ wtF,
                                                ushort_t* __restrict__ news) {
    const int tid = threadIdx.x;
    const int lane = tid & 63;
    const int hl = lane & 15, kg = lane >> 4;
    const int row0 = blockIdx.x * 128 + (tid >> 6) * 32;
    const int r0 = row0 + hl, r1 = r0 + 16;
    const bool ok0 = r0 < NN, ok1 = r1 < NN;
    const float* xr0 = &x[(long long)r0 * KE + kg * 8];
    const float* xr1 = &x[(long long)r1 * KE + kg * 8];
    const float4 fz = make_float4(0.f, 0.f, 0.f, 0.f);

    f32x4 acc0[8], acc1[8];
#pragma unroll
    for (int j = 0; j < 8; ++j) { acc0[j] = (f32x4)0.f; acc1[j] = (f32x4)0.f; }

    // prologue: chunk 0 raw A
    float4 c0a = ok0 ? ((const float4*)xr0)[0] : fz;
    float4 c0b = ok0 ? ((const float4*)xr0)[1] : fz;
    float4 c1a = ok1 ? ((const float4*)xr1)[0] : fz;
    float4 c1b = ok1 ? ((const float4*)xr1)[1] : fz;

#pragma unroll
    for (int c = 0; c < 9; ++c) {
        bf16x8 a0 = pack8(c0a, c0b);
        bf16x8 a1 = pack8(c1a, c1b);
        if (c < 8) {    // prefetch next full-vector chunk (chunks 1..8)
            const float4* p0 = (const float4*)(xr0 + (c + 1) * 32);
            const float4* p1 = (const float4*)(xr1 + (c + 1) * 32);
            c0a = ok0 ? p0[0] : fz;  c0b = ok0 ? p0[1] : fz;
            c1a = ok1 ? p1[0] : fz;  c1b = ok1 ? p1[1] : fz;
        }
        LOADB(c);
        MFMA16(a0, a1);
    }
    {   // tail chunk 9: cols 288..320 cross KE=300, masked loads
        bf16x8 a0 = loadA8m(x, r0, 288 + kg * 8, ok0);
        bf16x8 a1 = loadA8m(x, r1, 288 + kg * 8, ok1);
        LOADB(9);
        MFMA16(a0, a1);
    }
#pragma unroll
    for (int cf = 0; cf < 8; ++cf)
#pragma unroll
        for (int j = 0; j < 4; ++j) {
            int gr0 = row0 + kg * 4 + j;
            int gr1 = gr0 + 16;
            int gcol = cf * 16 + hl;
            if (gr0 < NN) news[(long long)gr0 * DD + gcol] = f2bf(acc0[cf][j]);
            if (gr1 < NN) news[(long long)gr1 * DD + gcol] = f2bf(acc1[cf][j]);
        }
}

// ---------------- partition: edges -> 1563 buckets of 64 dsts ---------------
__global__ __launch_bounds__(256) void k_part(const int* __restrict__ ei,
                                              unsigned* __restrict__ gcur,
                                              unsigned* __restrict__ pairs) {
    __shared__ unsigned hist[NBUCK], rbase[NBUCK], lcur[NBUCK];
    const int tid = threadIdx.x;
    const int eb = blockIdx.x * EPB;

    for (int i = tid; i < NBUCK; i += 256) hist[i] = 0;
    __syncthreads();

    unsigned val[EPT], bk[EPT];
#pragma unroll
    for (int l = 0; l < EPT; ++l) {
        int e = eb + l * 256 + tid;
        unsigned src = (unsigned)ei[e];
        unsigned dst = (unsigned)ei[NE + e];
        val[l] = (src << 6) | (dst & 63u);
        bk[l] = dst >> 6;
        atomicAdd(&hist[bk[l]], 1u);
    }
    __syncthreads();

    for (int i = tid; i < NBUCK; i += 256) {
        unsigned h = hist[i];
        rbase[i] = (unsigned)i * SLOT + (h ? atomicAdd(&gcur[i], h) : 0u);
        lcur[i] = 0;
    }
    __syncthreads();

#pragma unroll
    for (int l = 0; l < EPT; ++l) {
        unsigned b = bk[l];
        unsigned pos = rbase[b] + atomicAdd(&lcur[b], 1u);
        if (pos < (b + 1u) * SLOT) pairs[pos] = val[l];   // overflow guard
    }
}

// ---------------- bucket aggregate: 64-dst LDS CSR, 8 edges x 32B in flight -
__global__ __launch_bounds__(256) void k_bagg(const unsigned* __restrict__ gcur,
                                              const unsigned* __restrict__ pairs,
                                              const ushort_t* __restrict__ news,
                                              ushort_t* __restrict__ agg,
                                              int* __restrict__ deg) {
    __shared__ unsigned srcs[SLOT];
    __shared__ unsigned hist[64], base[64], cur[64];
    const int tid = threadIdx.x;
    const int b = blockIdx.x;
    int cnt = (int)gcur[b];
    if (cnt > SLOT) cnt = SLOT;

    if (tid < 64) hist[tid] = 0;
    __syncthreads();
    for (int i = tid; i < cnt; i += 256)
        atomicAdd(&hist[pairs[b * SLOT + i] & 63u], 1u);
    __syncthreads();

    // single-wave exclusive scan of 64 bins
    if (tid < 64) {
        unsigned h = hist[tid], v = h;
#pragma unroll
        for (int off = 1; off < 64; off <<= 1) {
            unsigned n = __shfl_up(v, off);
            if (tid >= off) v += n;
        }
        base[tid] = v - h;
        cur[tid]  = v - h;
    }
    __syncthreads();

    for (int i = tid; i < cnt; i += 256) {
        unsigned v = pairs[b * SLOT + i];
        srcs[atomicAdd(&cur[v & 63u], 1u)] = v >> 6;
    }
    __syncthreads();

    // wave per dst: 8 edge slots x 8 chunk lanes x 32B (two uint4 per lane)
    const int w = tid >> 6, lane = tid & 63;
    const int e = lane >> 3, l = lane & 7;
    for (int d = w; d < 64; d += 4) {
        int gd = b * 64 + d;
        if (gd >= NN) break;                 // uniform per wave
        int s0 = (int)base[d], c = (int)hist[d];
        float acc[16];
#pragma unroll
        for (int j = 0; j < 16; ++j) acc[j] = 0.f;
        for (int i = 0; i < c; i += 8) {
            int ii = i + e;
            uint4 va = make_uint4(0u, 0u, 0u, 0u);
            uint4 vb = make_uint4(0u, 0u, 0u, 0u);
            if (ii < c) {
                const uint4* P = (const uint4*)&news[(long long)srcs[s0 + ii] * DD + l * 16];
                va = P[0];
                vb = P[1];
            }
            acc[0]  += bf2f(va.x & 0xFFFFu); acc[1]  += bf2f(va.x >> 16);
            acc[2]  += bf2f(va.y & 0xFFFFu); acc[3]  += bf2f(va.y >> 16);
            acc[4]  += bf2f(va.z & 0xFFFFu); acc[5]  += bf2f(va.z >> 16);
            acc[6]  += bf2f(va.w & 0xFFFFu); acc[7]  += bf2f(va.w >> 16);
            acc[8]  += bf2f(vb.x & 0xFFFFu); acc[9]  += bf2f(vb.x >> 16);
            acc[10] += bf2f(vb.y & 0xFFFFu); acc[11] += bf2f(vb.y >> 16);
            acc[12] += bf2f(vb.z & 0xFFFFu); acc[13] += bf2f(vb.z >> 16);
            acc[14] += bf2f(vb.w & 0xFFFFu); acc[15] += bf2f(vb.w >> 16);
        }
        // reduce across the 8 edge slots (lane bits 3,4,5)
#pragma unroll
        for (int j = 0; j < 16; ++j) {
            acc[j] += __shfl_xor(acc[j], 8);
            acc[j] += __shfl_xor(acc[j], 16);
            acc[j] += __shfl_xor(acc[j], 32);
        }
        if (e == 0) {
            unsigned o[8];
#pragma unroll
            for (int j = 0; j < 8; ++j)
                o[j] = (unsigned)f2bf(acc[2 * j]) | ((unsigned)f2bf(acc[2 * j + 1]) << 16);
            uint4* Q = (uint4*)&agg[(long long)gd * DD + l * 16];
            Q[0] = make_uint4(o[0], o[1], o[2], o[3]);
            Q[1] = make_uint4(o[4], o[5], o[6], o[7]);
            if (l == 0) deg[gd] = c;
        }
    }
}

// ---------------- gnn: xx = f32(news) + (agg @ Wgnn) / deg ------------------
// No LDS, no barriers; A upfront, B fragment-major from L2.
__global__ __launch_bounds__(256) void gnn_mfma(const ushort_t* __restrict__ aggb,
                                                const ushort_t* __restrict__ wtF,
                                                const int* __restrict__ deg,
                                                const ushort_t* __restrict__ newsb,
                                                float* __restrict__ xx) {
    const int tid = threadIdx.x;
    const int lane = tid & 63;
    const int hl = lane & 15, kg = lane >> 4;
    const int row0 = blockIdx.x * 128 + (tid >> 6) * 32;
    const int r0 = row0 + hl, r1 = r0 + 16;
    const bool ok0 = r0 < NN, ok1 = r1 < NN;

    U4B a0[4], a1[4];
#pragma unroll
    for (int ks = 0; ks < 4; ++ks) {
        a0[ks].u = ok0 ? *(const uint4*)&aggb[(long long)r0 * DD + ks * 32 + kg * 8]
                       : make_uint4(0, 0, 0, 0);
        a1[ks].u = ok1 ? *(const uint4*)&aggb[(long long)r1 * DD + ks * 32 + kg * 8]
                       : make_uint4(0, 0, 0, 0);
    }

    f32x4 acc0[8], acc1[8];
#pragma unroll
    for (int j = 0; j < 8; ++j) { acc0[j] = (f32x4)0.f; acc1[j] = (f32x4)0.f; }

#pragma unroll
    for (int c = 0; c < 4; ++c) {
        LOADB(c);
        bf16x8 A0 = a0[c].b, A1 = a1[c].b;
        MFMA16(A0, A1);
    }

#pragma unroll
    for (int j = 0; j < 4; ++j) {
        int gr0 = row0 + kg * 4 + j;
        int gr1 = gr0 + 16;
        if (gr0 < NN) {
            float s = 1.f / fmaxf((float)deg[gr0], 1.f);
#pragma unroll
            for (int cf = 0; cf < 8; ++cf) {
                int gcol = cf * 16 + hl;
                float nv = bf2f((unsigned)newsb[(long long)gr0 * DD + gcol]);
                xx[(long long)gr0 * DD + gcol] = nv + acc0[cf][j] * s;
            }
        }
        if (gr1 < NN) {
            float s = 1.f / fmaxf((float)deg[gr1], 1.f);
#pragma unroll
            for (int cf = 0; cf < 8; ++cf) {
                int gcol = cf * 16 + hl;
                float nv = bf2f((unsigned)newsb[(long long)gr1 * DD + gcol]);
                xx[(long long)gr1 * DD + gcol] = nv + acc1[cf][j] * s;
            }
        }
    }
}

// ---------------- user vector: mean of masked history embeddings ------------
__global__ __launch_bounds__(128) void user_vec_k(const int* __restrict__ hist,
                                                  const float* __restrict__ xx,
                                                  float* __restrict__ uv) {
    int b = blockIdx.x, t = threadIdx.x;
    float s = 0.f, cnt = 0.f;
    for (int h = 0; h < HL; ++h) {
        int id = hist[b * HL + h];
        if (id != 0) { s += xx[(long long)id * DD + t]; cnt += 1.f; }
    }
    uv[b * DD + t] = s / fmaxf(cnt, 1e-9f);
}

// ---------------- scores: dot(cand_emb, user_vec) ---------------------------
__global__ __launch_bounds__(64) void scores_k(const int* __restrict__ cand,
                                               const float* __restrict__ xx,
                                               const float* __restrict__ uv,
                                               float* __restrict__ out) {
    int b = blockIdx.x, t = threadIdx.x;
    float u0 = uv[b * DD + t];
    float u1 = uv[b * DD + 64 + t];
    for (int c = 0; c < CL; ++c) {
        int id = cand[b * CL + c];
        float p = u0 * xx[(long long)id * DD + t] +
                  u1 * xx[(long long)id * DD + 64 + t];
#pragma unroll
        for (int off = 32; off >= 1; off >>= 1) p += __shfl_xor(p, off);
        if (t == 0) out[b * CL + c] = p;
    }
}

extern "C" void kernel_launch(void* const* d_in, const int* in_sizes, int n_in,
                              void* d_out, int out_size, void* d_ws, size_t ws_size,
                              hipStream_t stream) {
    const float* x    = (const float*)d_in[0];
    // d_in[1] = n_id == arange(N) -> identity scatter, unused
    const int*   ei   = (const int*)d_in[2];
    const int*   hist = (const int*)d_in[3];
    const int*   cand = (const int*)d_in[4];
    const float* Wenc = (const float*)d_in[5];
    const float* Wgnn = (const float*)d_in[6];
    float* out = (float*)d_out;

    float*    xx      = (float*)d_ws;                      // [NN*DD] f32
    float*    uv      = xx + (size_t)NN * DD;              // [NB*DD] f32
    ushort_t* news_bf = (ushort_t*)(uv + (size_t)NB * DD); // [NN*DD] bf16
    ushort_t* agg_bf  = news_bf + (size_t)NN * DD;         // [NN*DD] bf16
    ushort_t* wt_enc  = agg_bf + (size_t)NN * DD;          // [WTE_N]
    ushort_t* wt_gnn  = wt_enc + WTE_N;                    // [WTG_N]
    int*      deg     = (int*)(wt_gnn + WTG_N);            // [NN]
    unsigned* gcur    = (unsigned*)(deg + NN);             // [NBUCK]
    unsigned* pairs   = gcur + NBUCK;                      // [NBUCK*SLOT]

    hipMemsetAsync(gcur, 0, NBUCK * sizeof(unsigned), stream);

    prep_w<<<(WTE_N + WTG_N + 255) / 256, 256, 0, stream>>>(Wenc, Wgnn, wt_enc, wt_gnn);
    enc_mfma<<<(NN + 127) / 128, 256, 0, stream>>>(x, wt_enc, news_bf);

    k_part<<<PBLK, 256, 0, stream>>>(ei, gcur, pairs);
    k_bagg<<<NBUCK, 256, 0, stream>>>(gcur, pairs, news_bf, agg_bf, deg);

    gnn_mfma<<<(NN + 127) / 128, 256, 0, stream>>>(agg_bf, wt_gnn, deg, news_bf, xx);
    user_vec_k<<<NB, 128, 0, stream>>>(hist, xx, uv);
    scores_k<<<NB, 64, 0, stream>>>(cand, xx, uv, out);
}

// Round 11
// 202.829 us; speedup vs baseline: 1.1966x; 1.1966x over previous
//
#include <hip/hip_runtime.h>

#define NN 100000      // nodes
#define DD 128         // embedding dim
#define KE 300         // raw feature dim
#define NE 1600000     // edges
#define NB 4096        // batch (users)
#define HL 50          // history length
#define CL 20          // candidates

#define NBUCK 1563     // ceil(NN/64): buckets of 64 dst nodes
#define SLOT  1280     // max edges/bucket (mean 1024, sigma 32, +8 sigma)
#define PBLK  250      // partition blocks
#define EPB   6400     // edges per partition block
#define EPT   25       // edges per thread

#define WTE_N 40960    // 128 cols x 320 k, fragment-major
#define WTG_N 16384    // 128 cols x 128 k, fragment-major

typedef unsigned short ushort_t;
using bf16x8 = __attribute__((ext_vector_type(8))) short;
using f32x4  = __attribute__((ext_vector_type(4))) float;

union U4B { uint4 u; bf16x8 b; unsigned a[4]; };

__device__ __forceinline__ ushort_t f2bf(float f) {
    unsigned u = __float_as_uint(f);
    unsigned r = u + 0x7FFF + ((u >> 16) & 1);   // RNE
    return (ushort_t)(r >> 16);
}
__device__ __forceinline__ float bf2f(unsigned s) {
    return __uint_as_float(s << 16);
}
__device__ __forceinline__ bf16x8 pack8(float4 a, float4 b) {
    U4B r;
    r.a[0] = (unsigned)f2bf(a.x) | ((unsigned)f2bf(a.y) << 16);
    r.a[1] = (unsigned)f2bf(a.z) | ((unsigned)f2bf(a.w) << 16);
    r.a[2] = (unsigned)f2bf(b.x) | ((unsigned)f2bf(b.y) << 16);
    r.a[3] = (unsigned)f2bf(b.z) | ((unsigned)f2bf(b.w) << 16);
    return r.b;
}

// async global->LDS 16B (fire-and-forget, tracked by vmcnt)
__device__ __forceinline__ void glds16(const float* g, float* l) {
    __builtin_amdgcn_global_load_lds(
        (const __attribute__((address_space(1))) unsigned*)g,
        (__attribute__((address_space(3))) unsigned*)l, 16, 0, 0);
}

// ------- weight prep: fragment-major bf16 layouts ---------------------------
// wtF[((chunk*8+cf)*64 + lane)*8 + j] = W[k][n],
//   k = chunk*32 + (lane>>4)*8 + j,  n = cf*16 + (lane&15).
__global__ __launch_bounds__(256) void prep_w(const float* __restrict__ We,
                                              const float* __restrict__ Wg,
                                              ushort_t* __restrict__ wte,
                                              ushort_t* __restrict__ wtg) {
    int i = blockIdx.x * 256 + threadIdx.x;
    if (i < WTE_N) {
        int j = i & 7, lane = (i >> 3) & 63, cf = (i >> 9) & 7, ch = i >> 12;
        int k = ch * 32 + (lane >> 4) * 8 + j;
        int n = cf * 16 + (lane & 15);
        wte[i] = f2bf((k < KE) ? We[k * DD + n] : 0.f);
    } else if (i < WTE_N + WTG_N) {
        int t = i - WTE_N;
        int j = t & 7, lane = (t >> 3) & 63, cf = (t >> 9) & 7, ks = t >> 12;
        int k = ks * 32 + (lane >> 4) * 8 + j;
        int n = cf * 16 + (lane & 15);
        wtg[t] = f2bf(Wg[k * DD + n]);
    }
}

#define MFMA16(A0, A1)                                                          \
    do {                                                                        \
        acc0[0] = __builtin_amdgcn_mfma_f32_16x16x32_bf16(A0, b0, acc0[0], 0, 0, 0); \
        acc1[0] = __builtin_amdgcn_mfma_f32_16x16x32_bf16(A1, b0, acc1[0], 0, 0, 0); \
        acc0[1] = __builtin_amdgcn_mfma_f32_16x16x32_bf16(A0, b1, acc0[1], 0, 0, 0); \
        acc1[1] = __builtin_amdgcn_mfma_f32_16x16x32_bf16(A1, b1, acc1[1], 0, 0, 0); \
        acc0[2] = __builtin_amdgcn_mfma_f32_16x16x32_bf16(A0, b2, acc0[2], 0, 0, 0); \
        acc1[2] = __builtin_amdgcn_mfma_f32_16x16x32_bf16(A1, b2, acc1[2], 0, 0, 0); \
        acc0[3] = __builtin_amdgcn_mfma_f32_16x16x32_bf16(A0, b3, acc0[3], 0, 0, 0); \
        acc1[3] = __builtin_amdgcn_mfma_f32_16x16x32_bf16(A1, b3, acc1[3], 0, 0, 0); \
        acc0[4] = __builtin_amdgcn_mfma_f32_16x16x32_bf16(A0, b4, acc0[4], 0, 0, 0); \
        acc1[4] = __builtin_amdgcn_mfma_f32_16x16x32_bf16(A1, b4, acc1[4], 0, 0, 0); \
        acc0[5] = __builtin_amdgcn_mfma_f32_16x16x32_bf16(A0, b5, acc0[5], 0, 0, 0); \
        acc1[5] = __builtin_amdgcn_mfma_f32_16x16x32_bf16(A1, b5, acc1[5], 0, 0, 0); \
        acc0[6] = __builtin_amdgcn_mfma_f32_16x16x32_bf16(A0, b6, acc0[6], 0, 0, 0); \
        acc1[6] = __builtin_amdgcn_mfma_f32_16x16x32_bf16(A1, b6, acc1[6], 0, 0, 0); \
        acc0[7] = __builtin_amdgcn_mfma_f32_16x16x32_bf16(A0, b7, acc0[7], 0, 0, 0); \
        acc1[7] = __builtin_amdgcn_mfma_f32_16x16x32_bf16(A1, b7, acc1[7], 0, 0, 0); \
    } while (0)

#define LOADB(c)                                                                \
    const ushort_t* bp = &wtF[(c) * 8 * 512 + lane * 8];                        \
    bf16x8 b0 = *(const bf16x8*)&bp[0 * 512];                                   \
    bf16x8 b1 = *(const bf16x8*)&bp[1 * 512];                                   \
    bf16x8 b2 = *(const bf16x8*)&bp[2 * 512];                                   \
    bf16x8 b3 = *(const bf16x8*)&bp[3 * 512];                                   \
    bf16x8 b4 = *(const bf16x8*)&bp[4 * 512];                                   \
    bf16x8 b5 = *(const bf16x8*)&bp[5 * 512];                                   \
    bf16x8 b6 = *(const bf16x8*)&bp[6 * 512];                                   \
    bf16x8 b7 = *(const bf16x8*)&bp[7 * 512]

// ---------------- encoder: news_bf = bf16( x @ Wenc ) -----------------------
// m97-style: A fp32 tile (128x32, 16KB) double-buffered, staged via
// global_load_lds with pre-swizzled global source (linear LDS dest);
// ds_read_b128 with matching XOR swizzle (slot = r*8 + (c ^ (r&7))).
// B fragment-major from L2. 2 barriers per K-step.
__global__ __launch_bounds__(256) void enc_mfma(const float* __restrict__ x,
                                                const ushort_t* __restrict__ wtF,
                                                ushort_t* __restrict__ news) {
    __shared__ float As[2][4096];              // 2 x 128 rows x 32 k fp32
    const int tid = threadIdx.x;
    const int w = tid >> 6, lane = tid & 63;
    const int hl = lane & 15, kg = lane >> 4;
    const int row0 = blockIdx.x * 128;

    f32x4 acc0[8], acc1[8];
#pragma unroll
    for (int j = 0; j < 8; ++j) { acc0[j] = (f32x4)0.f; acc1[j] = (f32x4)0.f; }

    // async stage of K-step s into buffer nb (steps 0..8; k <= 287 < KE)
#define STAGE_GLDS(nb, s)                                                       \
    do {                                                                        \
        _Pragma("unroll")                                                       \
        for (int i = 0; i < 4; ++i) {                                           \
            int s4 = i * 256 + w * 64 + lane;      /* 16B slot 0..1023 */       \
            int r = s4 >> 3, c = (s4 & 7) ^ (r & 7);                            \
            int row = row0 + r;                                                 \
            if (row < NN)                                                       \
                glds16(&x[(long long)row * KE + (s) * 32 + c * 4],              \
                       &As[nb][0] + i * 1024 + w * 256);                        \
        }                                                                       \
    } while (0)

    STAGE_GLDS(0, 0);
    __syncthreads();

#pragma unroll
    for (int s = 0; s < 10; ++s) {
        const int cb = s & 1, nb = cb ^ 1;
        if (s < 8) {
            STAGE_GLDS(nb, s + 1);
        } else if (s == 8) {
            // manual stage of step 9 (k 288..319 crosses KE=300 / array end)
#pragma unroll
            for (int i = 0; i < 4; ++i) {
                int s4 = i * 256 + w * 64 + lane;
                int r = s4 >> 3, c = (s4 & 7) ^ (r & 7);
                int row = row0 + r;
                int k = 288 + c * 4;
                float4 v = make_float4(0.f, 0.f, 0.f, 0.f);
                if (row < NN && k + 4 <= KE)
                    v = *(const float4*)&x[(long long)row * KE + k];
                *(float4*)&As[nb][s4 * 4] = v;
            }
        }
        // A fragments from current buffer (swizzled ds_read_b128 x4)
        const int r0f = w * 32 + hl, r1f = r0f + 16;
        const int sw = hl & 7;
        float4 v00 = *(const float4*)&As[cb][(r0f * 8 + ((kg * 2)     ^ sw)) * 4];
        float4 v01 = *(const float4*)&As[cb][(r0f * 8 + ((kg * 2 + 1) ^ sw)) * 4];
        float4 v10 = *(const float4*)&As[cb][(r1f * 8 + ((kg * 2)     ^ sw)) * 4];
        float4 v11 = *(const float4*)&As[cb][(r1f * 8 + ((kg * 2 + 1) ^ sw)) * 4];
        bf16x8 a0 = pack8(v00, v01);
        bf16x8 a1 = pack8(v10, v11);
        LOADB(s);
        MFMA16(a0, a1);
        __syncthreads();
    }
#undef STAGE_GLDS

#pragma unroll
    for (int cf = 0; cf < 8; ++cf)
#pragma unroll
        for (int j = 0; j < 4; ++j) {
            int gr0 = row0 + w * 32 + kg * 4 + j;
            int gr1 = gr0 + 16;
            int gcol = cf * 16 + hl;
            if (gr0 < NN) news[(long long)gr0 * DD + gcol] = f2bf(acc0[cf][j]);
            if (gr1 < NN) news[(long long)gr1 * DD + gcol] = f2bf(acc1[cf][j]);
        }
}

// ---------------- partition: edges -> 1563 buckets of 64 dsts ---------------
__global__ __launch_bounds__(256) void k_part(const int* __restrict__ ei,
                                              unsigned* __restrict__ gcur,
                                              unsigned* __restrict__ pairs) {
    __shared__ unsigned hist[NBUCK], rbase[NBUCK], lcur[NBUCK];
    const int tid = threadIdx.x;
    const int eb = blockIdx.x * EPB;

    for (int i = tid; i < NBUCK; i += 256) hist[i] = 0;
    __syncthreads();

    unsigned val[EPT], bk[EPT];
#pragma unroll
    for (int l = 0; l < EPT; ++l) {
        int e = eb + l * 256 + tid;
        unsigned src = (unsigned)ei[e];
        unsigned dst = (unsigned)ei[NE + e];
        val[l] = (src << 6) | (dst & 63u);
        bk[l] = dst >> 6;
        atomicAdd(&hist[bk[l]], 1u);
    }
    __syncthreads();

    for (int i = tid; i < NBUCK; i += 256) {
        unsigned h = hist[i];
        rbase[i] = (unsigned)i * SLOT + (h ? atomicAdd(&gcur[i], h) : 0u);
        lcur[i] = 0;
    }
    __syncthreads();

#pragma unroll
    for (int l = 0; l < EPT; ++l) {
        unsigned b = bk[l];
        unsigned pos = rbase[b] + atomicAdd(&lcur[b], 1u);
        if (pos < (b + 1u) * SLOT) pairs[pos] = val[l];   // overflow guard
    }
}

// ---------------- bucket aggregate: 64-dst LDS CSR + pipelined gather -------
__global__ __launch_bounds__(256) void k_bagg(const unsigned* __restrict__ gcur,
                                              const unsigned* __restrict__ pairs,
                                              const ushort_t* __restrict__ news,
                                              ushort_t* __restrict__ agg,
                                              int* __restrict__ deg) {
    __shared__ unsigned srcs[SLOT];
    __shared__ unsigned hist[64], base[64], cur[64];
    const int tid = threadIdx.x;
    const int b = blockIdx.x;
    int cnt = (int)gcur[b];
    if (cnt > SLOT) cnt = SLOT;

    if (tid < 64) hist[tid] = 0;
    __syncthreads();
    for (int i = tid; i < cnt; i += 256)
        atomicAdd(&hist[pairs[b * SLOT + i] & 63u], 1u);
    __syncthreads();

    // single-wave exclusive scan of 64 bins
    if (tid < 64) {
        unsigned h = hist[tid], v = h;
#pragma unroll
        for (int off = 1; off < 64; off <<= 1) {
            unsigned n = __shfl_up(v, off);
            if (tid >= off) v += n;
        }
        base[tid] = v - h;
        cur[tid]  = v - h;
    }
    __syncthreads();

    for (int i = tid; i < cnt; i += 256) {
        unsigned v = pairs[b * SLOT + i];
        srcs[atomicAdd(&cur[v & 63u], 1u)] = v >> 6;
    }
    __syncthreads();

    // wave per dst: 4 edge slots, depth-2 pipeline (8 gathers in flight)
    const int w = tid >> 6, lane = tid & 63;
    const int e = lane >> 4, l = lane & 15;
    for (int d = w; d < 64; d += 4) {
        int gd = b * 64 + d;
        if (gd >= NN) break;                 // uniform per wave
        int s0 = (int)base[d], c = (int)hist[d];
        float acc[8];
#pragma unroll
        for (int j = 0; j < 8; ++j) acc[j] = 0.f;

        uint4 v = make_uint4(0u, 0u, 0u, 0u);
        if (e < c)
            v = *(const uint4*)&news[(long long)srcs[s0 + e] * DD + l * 8];
        for (int i = 4; i < c; i += 4) {
            uint4 vn = make_uint4(0u, 0u, 0u, 0u);
            int ii = i + e;
            if (ii < c)
                vn = *(const uint4*)&news[(long long)srcs[s0 + ii] * DD + l * 8];
            acc[0] += bf2f(v.x & 0xFFFFu); acc[1] += bf2f(v.x >> 16);
            acc[2] += bf2f(v.y & 0xFFFFu); acc[3] += bf2f(v.y >> 16);
            acc[4] += bf2f(v.z & 0xFFFFu); acc[5] += bf2f(v.z >> 16);
            acc[6] += bf2f(v.w & 0xFFFFu); acc[7] += bf2f(v.w >> 16);
            v = vn;
        }
        acc[0] += bf2f(v.x & 0xFFFFu); acc[1] += bf2f(v.x >> 16);
        acc[2] += bf2f(v.y & 0xFFFFu); acc[3] += bf2f(v.y >> 16);
        acc[4] += bf2f(v.z & 0xFFFFu); acc[5] += bf2f(v.z >> 16);
        acc[6] += bf2f(v.w & 0xFFFFu); acc[7] += bf2f(v.w >> 16);

#pragma unroll
        for (int j = 0; j < 8; ++j) {
            acc[j] += __shfl_xor(acc[j], 16);
            acc[j] += __shfl_xor(acc[j], 32);
        }
        if (e == 0) {
            uint4 o;
            o.x = (unsigned)f2bf(acc[0]) | ((unsigned)f2bf(acc[1]) << 16);
            o.y = (unsigned)f2bf(acc[2]) | ((unsigned)f2bf(acc[3]) << 16);
            o.z = (unsigned)f2bf(acc[4]) | ((unsigned)f2bf(acc[5]) << 16);
            o.w = (unsigned)f2bf(acc[6]) | ((unsigned)f2bf(acc[7]) << 16);
            *(uint4*)&agg[(long long)gd * DD + l * 8] = o;
            if (l == 0) deg[gd] = c;
        }
    }
}

// ---------------- gnn: xx = f32(news) + (agg @ Wgnn) / deg ------------------
// No LDS, no barriers; A upfront, B fragment-major from L2 (R8 form).
__global__ __launch_bounds__(256) void gnn_mfma(const ushort_t* __restrict__ aggb,
                                                const ushort_t* __restrict__ wtF,
                                                const int* __restrict__ deg,
                                                const ushort_t* __restrict__ newsb,
                                                float* __restrict__ xx) {
    const int tid = threadIdx.x;
    const int lane = tid & 63;
    const int hl = lane & 15, kg = lane >> 4;
    const int row0 = blockIdx.x * 64 + (tid >> 6) * 16;
    const int r0 = row0 + hl;
    const bool ok0 = r0 < NN;

    U4B a[4];
#pragma unroll
    for (int ks = 0; ks < 4; ++ks)
        a[ks].u = ok0 ? *(const uint4*)&aggb[(long long)r0 * DD + ks * 32 + kg * 8]
                      : make_uint4(0, 0, 0, 0);

    f32x4 acc[8];
#pragma unroll
    for (int j = 0; j < 8; ++j) acc[j] = (f32x4)0.f;

#pragma unroll
    for (int ks = 0; ks < 4; ++ks) {
        const ushort_t* bp = &wtF[(ks * 8) * 512 + lane * 8];
#pragma unroll
        for (int cf = 0; cf < 8; ++cf) {
            bf16x8 bfr = *(const bf16x8*)&bp[cf * 512];
            acc[cf] = __builtin_amdgcn_mfma_f32_16x16x32_bf16(a[ks].b, bfr, acc[cf], 0, 0, 0);
        }
    }

#pragma unroll
    for (int j = 0; j < 4; ++j) {
        int grow = row0 + kg * 4 + j;
        if (grow < NN) {
            float s = 1.f / fmaxf((float)deg[grow], 1.f);
#pragma unroll
            for (int cf = 0; cf < 8; ++cf) {
                int gcol = cf * 16 + hl;
                float nv = bf2f((unsigned)newsb[(long long)grow * DD + gcol]);
                xx[(long long)grow * DD + gcol] = nv + acc[cf][j] * s;
            }
        }
    }
}

// ---------------- user vector: mean of masked history embeddings ------------
__global__ __launch_bounds__(128) void user_vec_k(const int* __restrict__ hist,
                                                  const float* __restrict__ xx,
                                                  float* __restrict__ uv) {
    int b = blockIdx.x, t = threadIdx.x;
    float s = 0.f, cnt = 0.f;
    for (int h = 0; h < HL; ++h) {
        int id = hist[b * HL + h];
        if (id != 0) { s += xx[(long long)id * DD + t]; cnt += 1.f; }
    }
    uv[b * DD + t] = s / fmaxf(cnt, 1e-9f);
}

// ---------------- scores: dot(cand_emb, user_vec) ---------------------------
__global__ __launch_bounds__(64) void scores_k(const int* __restrict__ cand,
                                               const float* __restrict__ xx,
                                               const float* __restrict__ uv,
                                               float* __restrict__ out) {
    int b = blockIdx.x, t = threadIdx.x;
    float u0 = uv[b * DD + t];
    float u1 = uv[b * DD + 64 + t];
    for (int c = 0; c < CL; ++c) {
        int id = cand[b * CL + c];
        float p = u0 * xx[(long long)id * DD + t] +
                  u1 * xx[(long long)id * DD + 64 + t];
#pragma unroll
        for (int off = 32; off >= 1; off >>= 1) p += __shfl_xor(p, off);
        if (t == 0) out[b * CL + c] = p;
    }
}

extern "C" void kernel_launch(void* const* d_in, const int* in_sizes, int n_in,
                              void* d_out, int out_size, void* d_ws, size_t ws_size,
                              hipStream_t stream) {
    const float* x    = (const float*)d_in[0];
    // d_in[1] = n_id == arange(N) -> identity scatter, unused
    const int*   ei   = (const int*)d_in[2];
    const int*   hist = (const int*)d_in[3];
    const int*   cand = (const int*)d_in[4];
    const float* Wenc = (const float*)d_in[5];
    const float* Wgnn = (const float*)d_in[6];
    float* out = (float*)d_out;

    float*    xx      = (float*)d_ws;                      // [NN*DD] f32
    float*    uv      = xx + (size_t)NN * DD;              // [NB*DD] f32
    ushort_t* news_bf = (ushort_t*)(uv + (size_t)NB * DD); // [NN*DD] bf16
    ushort_t* agg_bf  = news_bf + (size_t)NN * DD;         // [NN*DD] bf16
    ushort_t* wt_enc  = agg_bf + (size_t)NN * DD;          // [WTE_N]
    ushort_t* wt_gnn  = wt_enc + WTE_N;                    // [WTG_N]
    int*      deg     = (int*)(wt_gnn + WTG_N);            // [NN]
    unsigned* gcur    = (unsigned*)(deg + NN);             // [NBUCK]
    unsigned* pairs   = gcur + NBUCK;                      // [NBUCK*SLOT]

    hipMemsetAsync(gcur, 0, NBUCK * sizeof(unsigned), stream);

    prep_w<<<(WTE_N + WTG_N + 255) / 256, 256, 0, stream>>>(Wenc, Wgnn, wt_enc, wt_gnn);
    enc_mfma<<<(NN + 127) / 128, 256, 0, stream>>>(x, wt_enc, news_bf);

    k_part<<<PBLK, 256, 0, stream>>>(ei, gcur, pairs);
    k_bagg<<<NBUCK, 256, 0, stream>>>(gcur, pairs, news_bf, agg_bf, deg);

    gnn_mfma<<<(NN + 63) / 64, 256, 0, stream>>>(agg_bf, wt_gnn, deg, news_bf, xx);
    user_vec_k<<<NB, 128, 0, stream>>>(hist, xx, uv);
    scores_k<<<NB, 64, 0, stream>>>(cand, xx, uv, out);
}

// Round 12
// 179.351 us; speedup vs baseline: 1.3533x; 1.1309x over previous
//
#include <hip/hip_runtime.h>

#define NN 100000      // nodes
#define DD 128         // embedding dim
#define KE 300         // raw feature dim
#define NE 1600000     // edges
#define NB 4096        // batch (users)
#define HL 50          // history length
#define CL 20          // candidates

#define NBUCK 1563     // ceil(NN/64): buckets of 64 dst nodes
#define SLOT  1280     // max edges/bucket (mean 1024, sigma 32, +8 sigma)
#define PBLK  250      // partition blocks
#define EPB   6400     // edges per partition block
#define EPT   25       // edges per thread
#define EBLK  1563     // enc blocks (64 rows each)

#define WTE_N 40960    // 128 cols x 320 k, fragment-major
#define WTG_N 16384    // 128 cols x 128 k, fragment-major

typedef unsigned short ushort_t;
using bf16x8 = __attribute__((ext_vector_type(8))) short;
using f32x4  = __attribute__((ext_vector_type(4))) float;

union U4B { uint4 u; bf16x8 b; unsigned a[4]; };

__device__ __forceinline__ ushort_t f2bf(float f) {
    unsigned u = __float_as_uint(f);
    unsigned r = u + 0x7FFF + ((u >> 16) & 1);   // RNE
    return (ushort_t)(r >> 16);
}
__device__ __forceinline__ float bf2f(unsigned s) {
    return __uint_as_float(s << 16);
}
__device__ __forceinline__ bf16x8 pack8(float4 a, float4 b) {
    U4B r;
    r.a[0] = (unsigned)f2bf(a.x) | ((unsigned)f2bf(a.y) << 16);
    r.a[1] = (unsigned)f2bf(a.z) | ((unsigned)f2bf(a.w) << 16);
    r.a[2] = (unsigned)f2bf(b.x) | ((unsigned)f2bf(b.y) << 16);
    r.a[3] = (unsigned)f2bf(b.z) | ((unsigned)f2bf(b.w) << 16);
    return r.b;
}

// ------- weight prep: fragment-major bf16 layouts ---------------------------
// wtF[((chunk*8+cf)*64 + lane)*8 + j] = W[k][n],
//   k = chunk*32 + (lane>>4)*8 + j,  n = cf*16 + (lane&15).
__global__ __launch_bounds__(256) void prep_w(const float* __restrict__ We,
                                              const float* __restrict__ Wg,
                                              ushort_t* __restrict__ wte,
                                              ushort_t* __restrict__ wtg) {
    int i = blockIdx.x * 256 + threadIdx.x;
    if (i < WTE_N) {
        int j = i & 7, lane = (i >> 3) & 63, cf = (i >> 9) & 7, ch = i >> 12;
        int k = ch * 32 + (lane >> 4) * 8 + j;
        int n = cf * 16 + (lane & 15);
        wte[i] = f2bf((k < KE) ? We[k * DD + n] : 0.f);
    } else if (i < WTE_N + WTG_N) {
        int t = i - WTE_N;
        int j = t & 7, lane = (t >> 3) & 63, cf = (t >> 9) & 7, ks = t >> 12;
        int k = ks * 32 + (lane >> 4) * 8 + j;
        int n = cf * 16 + (lane & 15);
        wtg[t] = f2bf(Wg[k * DD + n]);
    }
}

// ---- A fragment loader: 8 consecutive fp32 -> bf16x8 (zero past edges) -----
__device__ __forceinline__ bf16x8 loadA8(const float* __restrict__ x,
                                         int row, int col, bool rowok) {
    float v[8];
    if (rowok && col + 8 <= KE) {
        const float4* p = (const float4*)&x[(long long)row * KE + col];
        float4 a = p[0], b = p[1];
        v[0]=a.x; v[1]=a.y; v[2]=a.z; v[3]=a.w;
        v[4]=b.x; v[5]=b.y; v[6]=b.z; v[7]=b.w;
    } else {
#pragma unroll
        for (int j = 0; j < 8; ++j) {
            int c = col + j;
            v[j] = (rowok && c < KE) ? x[(long long)row * KE + c] : 0.f;
        }
    }
    return pack8(make_float4(v[0], v[1], v[2], v[3]),
                 make_float4(v[4], v[5], v[6], v[7]));
}

// ---------------- fused front: partition (blocks < PBLK) + encoder ----------
// Independent subgraphs share one dispatch so k_part hides under enc.
__global__ __launch_bounds__(256) void k_front(const float* __restrict__ x,
                                               const ushort_t* __restrict__ wtF,
                                               const int* __restrict__ ei,
                                               unsigned* __restrict__ gcur,
                                               unsigned* __restrict__ pairs,
                                               ushort_t* __restrict__ news) {
    __shared__ unsigned sh[NBUCK], sb[NBUCK], sc[NBUCK];
    const int tid = threadIdx.x;

    if (blockIdx.x < PBLK) {
        // ---------- partition: edges -> 1563 buckets of 64 dsts ----------
        const int eb = blockIdx.x * EPB;
        for (int i = tid; i < NBUCK; i += 256) sh[i] = 0;
        __syncthreads();

        unsigned val[EPT], bk[EPT];
#pragma unroll
        for (int l = 0; l < EPT; ++l) {
            int e = eb + l * 256 + tid;
            unsigned src = (unsigned)ei[e];
            unsigned dst = (unsigned)ei[NE + e];
            val[l] = (src << 6) | (dst & 63u);
            bk[l] = dst >> 6;
            atomicAdd(&sh[bk[l]], 1u);
        }
        __syncthreads();

        for (int i = tid; i < NBUCK; i += 256) {
            unsigned h = sh[i];
            sb[i] = (unsigned)i * SLOT + (h ? atomicAdd(&gcur[i], h) : 0u);
            sc[i] = 0;
        }
        __syncthreads();

#pragma unroll
        for (int l = 0; l < EPT; ++l) {
            unsigned b = bk[l];
            unsigned pos = sb[b] + atomicAdd(&sc[b], 1u);
            if (pos < (b + 1u) * SLOT) pairs[pos] = val[l];   // overflow guard
        }
        return;
    }

    // ---------- encoder: news_bf = bf16( x @ Wenc ), R8 structure ----------
    const int lane = tid & 63;
    const int hl = lane & 15, kg = lane >> 4;
    const int row0 = (blockIdx.x - PBLK) * 64 + (tid >> 6) * 16;
    const int r0 = row0 + hl;
    const bool ok0 = r0 < NN;

    f32x4 acc[8];
#pragma unroll
    for (int j = 0; j < 8; ++j) acc[j] = (f32x4)0.f;

#pragma unroll
    for (int p = 0; p < 5; ++p) {
        bf16x8 a0 = loadA8(x, r0, p * 64 + kg * 8, ok0);
        bf16x8 a1 = loadA8(x, r0, p * 64 + 32 + kg * 8, ok0);
#pragma unroll
        for (int ks = 0; ks < 2; ++ks) {
            bf16x8 af = ks ? a1 : a0;
            const ushort_t* bp = &wtF[((p * 2 + ks) * 8) * 512 + lane * 8];
#pragma unroll
            for (int cf = 0; cf < 8; ++cf) {
                bf16x8 bfr = *(const bf16x8*)&bp[cf * 512];
                acc[cf] = __builtin_amdgcn_mfma_f32_16x16x32_bf16(af, bfr, acc[cf], 0, 0, 0);
            }
        }
    }
#pragma unroll
    for (int cf = 0; cf < 8; ++cf)
#pragma unroll
        for (int j = 0; j < 4; ++j) {
            int grow = row0 + kg * 4 + j;
            int gcol = cf * 16 + hl;
            if (grow < NN)
                news[(long long)grow * DD + gcol] = f2bf(acc[cf][j]);
        }
}

// ------- fused bucket aggregate + GNN GEMM + epilogue -----------------------
// Phase A: 64-dst LDS CSR + register gather -> agg rows kept in LDS (bf16,
// chunk-XOR swizzle, natural 256B stride -> <=2-way conflicts).
// Phase B: 64-row MFMA vs wt_gnn (fragment-major L2) + residual epilogue.
__global__ __launch_bounds__(256) void k_baggnn(const unsigned* __restrict__ gcur,
                                                const unsigned* __restrict__ pairs,
                                                const ushort_t* __restrict__ news,
                                                const ushort_t* __restrict__ wtF,
                                                float* __restrict__ xx) {
    __shared__ unsigned srcs[SLOT];
    __shared__ unsigned hist[64], base[64], cur[64];
    __shared__ ushort_t aggs[64 * DD];         // 16 KB, swizzled 16B chunks
    const int tid = threadIdx.x;
    const int b = blockIdx.x;
    int cnt = (int)gcur[b];
    if (cnt > SLOT) cnt = SLOT;

    if (tid < 64) hist[tid] = 0;
    __syncthreads();
    for (int i = tid; i < cnt; i += 256)
        atomicAdd(&hist[pairs[b * SLOT + i] & 63u], 1u);
    __syncthreads();

    // single-wave exclusive scan of 64 bins
    if (tid < 64) {
        unsigned h = hist[tid], v = h;
#pragma unroll
        for (int off = 1; off < 64; off <<= 1) {
            unsigned n = __shfl_up(v, off);
            if (tid >= off) v += n;
        }
        base[tid] = v - h;
        cur[tid]  = v - h;
    }
    __syncthreads();

    for (int i = tid; i < cnt; i += 256) {
        unsigned v = pairs[b * SLOT + i];
        srcs[atomicAdd(&cur[v & 63u], 1u)] = v >> 6;
    }
    __syncthreads();

    // ---- phase A: wave per dst, 4 edges in flight, depth-2 pipeline ----
    const int w = tid >> 6, lane = tid & 63;
    const int e = lane >> 4, l = lane & 15;
    for (int d = w; d < 64; d += 4) {
        int gd = b * 64 + d;
        if (gd >= NN) break;                 // uniform per wave
        int s0 = (int)base[d], c = (int)hist[d];
        float acc[8];
#pragma unroll
        for (int j = 0; j < 8; ++j) acc[j] = 0.f;

        uint4 v = make_uint4(0u, 0u, 0u, 0u);
        if (e < c)
            v = *(const uint4*)&news[(long long)srcs[s0 + e] * DD + l * 8];
        for (int i = 4; i < c; i += 4) {
            uint4 vn = make_uint4(0u, 0u, 0u, 0u);
            int ii = i + e;
            if (ii < c)
                vn = *(const uint4*)&news[(long long)srcs[s0 + ii] * DD + l * 8];
            acc[0] += bf2f(v.x & 0xFFFFu); acc[1] += bf2f(v.x >> 16);
            acc[2] += bf2f(v.y & 0xFFFFu); acc[3] += bf2f(v.y >> 16);
            acc[4] += bf2f(v.z & 0xFFFFu); acc[5] += bf2f(v.z >> 16);
            acc[6] += bf2f(v.w & 0xFFFFu); acc[7] += bf2f(v.w >> 16);
            v = vn;
        }
        acc[0] += bf2f(v.x & 0xFFFFu); acc[1] += bf2f(v.x >> 16);
        acc[2] += bf2f(v.y & 0xFFFFu); acc[3] += bf2f(v.y >> 16);
        acc[4] += bf2f(v.z & 0xFFFFu); acc[5] += bf2f(v.z >> 16);
        acc[6] += bf2f(v.w & 0xFFFFu); acc[7] += bf2f(v.w >> 16);

#pragma unroll
        for (int j = 0; j < 8; ++j) {
            acc[j] += __shfl_xor(acc[j], 16);
            acc[j] += __shfl_xor(acc[j], 32);
        }
        if (e == 0) {
            uint4 o;
            o.x = (unsigned)f2bf(acc[0]) | ((unsigned)f2bf(acc[1]) << 16);
            o.y = (unsigned)f2bf(acc[2]) | ((unsigned)f2bf(acc[3]) << 16);
            o.z = (unsigned)f2bf(acc[4]) | ((unsigned)f2bf(acc[5]) << 16);
            o.w = (unsigned)f2bf(acc[6]) | ((unsigned)f2bf(acc[7]) << 16);
            *(uint4*)&aggs[d * DD + (l ^ (d & 15)) * 8] = o;   // swizzled chunk
        }
    }
    __syncthreads();

    // ---- phase B: gnn MFMA on the 64 LDS rows ----
    const int hl = lane & 15, kg = lane >> 4;
    U4B a[4];
#pragma unroll
    for (int ks = 0; ks < 4; ++ks)
        a[ks].u = *(const uint4*)&aggs[(w * 16 + hl) * DD + ((ks * 4 + kg) ^ hl) * 8];

    f32x4 acc[8];
#pragma unroll
    for (int j = 0; j < 8; ++j) acc[j] = (f32x4)0.f;

#pragma unroll
    for (int ks = 0; ks < 4; ++ks) {
        const ushort_t* bp = &wtF[(ks * 8) * 512 + lane * 8];
#pragma unroll
        for (int cf = 0; cf < 8; ++cf) {
            bf16x8 bfr = *(const bf16x8*)&bp[cf * 512];
            acc[cf] = __builtin_amdgcn_mfma_f32_16x16x32_bf16(a[ks].b, bfr, acc[cf], 0, 0, 0);
        }
    }

#pragma unroll
    for (int j = 0; j < 4; ++j) {
        int lr = w * 16 + kg * 4 + j;
        int grow = b * 64 + lr;
        if (grow < NN) {
            float s = 1.f / fmaxf((float)hist[lr], 1.f);
#pragma unroll
            for (int cf = 0; cf < 8; ++cf) {
                int gcol = cf * 16 + hl;
                float nv = bf2f((unsigned)news[(long long)grow * DD + gcol]);
                xx[(long long)grow * DD + gcol] = nv + acc[cf][j] * s;
            }
        }
    }
}

// ---------------- fused user vector + scores --------------------------------
__global__ __launch_bounds__(128) void k_user(const int* __restrict__ hist,
                                              const int* __restrict__ cand,
                                              const float* __restrict__ xx,
                                              float* __restrict__ out) {
    __shared__ float uvs[128];
    const int b = blockIdx.x, t = threadIdx.x;

    float s = 0.f, cnt = 0.f;
    for (int h = 0; h < HL; ++h) {
        int id = hist[b * HL + h];
        if (id != 0) { s += xx[(long long)id * DD + t]; cnt += 1.f; }
    }
    uvs[t] = s / fmaxf(cnt, 1e-9f);
    __syncthreads();

    const int w = t >> 6, lane = t & 63;
    float2 uvp = *(const float2*)&uvs[lane * 2];
    for (int c = w; c < CL; c += 2) {
        int id = cand[b * CL + c];
        float2 xv = *(const float2*)&xx[(long long)id * DD + lane * 2];
        float p = uvp.x * xv.x + uvp.y * xv.y;
#pragma unroll
        for (int off = 32; off >= 1; off >>= 1) p += __shfl_xor(p, off);
        if (lane == 0) out[b * CL + c] = p;
    }
}

extern "C" void kernel_launch(void* const* d_in, const int* in_sizes, int n_in,
                              void* d_out, int out_size, void* d_ws, size_t ws_size,
                              hipStream_t stream) {
    const float* x    = (const float*)d_in[0];
    // d_in[1] = n_id == arange(N) -> identity scatter, unused
    const int*   ei   = (const int*)d_in[2];
    const int*   hist = (const int*)d_in[3];
    const int*   cand = (const int*)d_in[4];
    const float* Wenc = (const float*)d_in[5];
    const float* Wgnn = (const float*)d_in[6];
    float* out = (float*)d_out;

    float*    xx      = (float*)d_ws;                      // [NN*DD] f32
    ushort_t* news_bf = (ushort_t*)(xx + (size_t)NN * DD); // [NN*DD] bf16
    ushort_t* wt_enc  = news_bf + (size_t)NN * DD;         // [WTE_N]
    ushort_t* wt_gnn  = wt_enc + WTE_N;                    // [WTG_N]
    unsigned* gcur    = (unsigned*)(wt_gnn + WTG_N);       // [NBUCK]
    unsigned* pairs   = gcur + NBUCK;                      // [NBUCK*SLOT]

    hipMemsetAsync(gcur, 0, NBUCK * sizeof(unsigned), stream);

    prep_w<<<(WTE_N + WTG_N + 255) / 256, 256, 0, stream>>>(Wenc, Wgnn, wt_enc, wt_gnn);
    k_front<<<PBLK + EBLK, 256, 0, stream>>>(x, wt_enc, ei, gcur, pairs, news_bf);
    k_baggnn<<<NBUCK, 256, 0, stream>>>(gcur, pairs, news_bf, wt_gnn, xx);
    k_user<<<NB, 128, 0, stream>>>(hist, cand, xx, out);
}

// Round 13
// 169.411 us; speedup vs baseline: 1.4327x; 1.0587x over previous
//
#include <hip/hip_runtime.h>

#define NN 100000      // nodes
#define DD 128         // embedding dim
#define KE 300         // raw feature dim
#define NE 1600000     // edges
#define NB 4096        // batch (users)
#define HL 50          // history length
#define CL 20          // candidates

#define NBUCK 1563     // ceil(NN/64): buckets of 64 dst nodes
#define SLOT  1280     // max edges/bucket (mean 1024, sigma 32, +8 sigma)
#define PBLK  250      // partition blocks
#define EPB   6400     // edges per partition block
#define EPT   25       // edges per thread
#define EBLK  1563     // enc row-tiles (64 rows each)

#define WTE_N 40960    // 128 cols x 320 k, fragment-major
#define WTG_N 16384    // 128 cols x 128 k, fragment-major
#define PREPB ((WTE_N + WTG_N + 255) / 256)   // 224 weight-prep blocks

typedef unsigned short ushort_t;
using bf16x8 = __attribute__((ext_vector_type(8))) short;
using f32x4  = __attribute__((ext_vector_type(4))) float;

union U4B { uint4 u; bf16x8 b; unsigned a[4]; };

__device__ __forceinline__ ushort_t f2bf(float f) {
    unsigned u = __float_as_uint(f);
    unsigned r = u + 0x7FFF + ((u >> 16) & 1);   // RNE
    return (ushort_t)(r >> 16);
}
__device__ __forceinline__ float bf2f(unsigned s) {
    return __uint_as_float(s << 16);
}
__device__ __forceinline__ bf16x8 pack8(float4 a, float4 b) {
    U4B r;
    r.a[0] = (unsigned)f2bf(a.x) | ((unsigned)f2bf(a.y) << 16);
    r.a[1] = (unsigned)f2bf(a.z) | ((unsigned)f2bf(a.w) << 16);
    r.a[2] = (unsigned)f2bf(b.x) | ((unsigned)f2bf(b.y) << 16);
    r.a[3] = (unsigned)f2bf(b.z) | ((unsigned)f2bf(b.w) << 16);
    return r.b;
}

// ---- masked A fragment loader (tail chunk crossing KE) ---------------------
__device__ __forceinline__ bf16x8 loadA8m(const float* __restrict__ x,
                                          int row, int col, bool rowok) {
    float v[8];
#pragma unroll
    for (int j = 0; j < 8; ++j) {
        int c = col + j;
        v[j] = (rowok && c < KE) ? x[(long long)row * KE + c] : 0.f;
    }
    return pack8(make_float4(v[0], v[1], v[2], v[3]),
                 make_float4(v[4], v[5], v[6], v[7]));
}

// ------- fused prep: edge partition (blocks < PBLK) + weight transpose ------
// Both are independent of everything else; one dispatch hides the partition.
// wtF[((chunk*8+cf)*64 + lane)*8 + j] = W[k][n],
//   k = chunk*32 + (lane>>4)*8 + j,  n = cf*16 + (lane&15).
__global__ __launch_bounds__(256) void k_prep(const int* __restrict__ ei,
                                              unsigned* __restrict__ gcur,
                                              unsigned* __restrict__ pairs,
                                              const float* __restrict__ We,
                                              const float* __restrict__ Wg,
                                              ushort_t* __restrict__ wte,
                                              ushort_t* __restrict__ wtg) {
    __shared__ unsigned sh[NBUCK], sb[NBUCK], sc[NBUCK];
    const int tid = threadIdx.x;

    if (blockIdx.x < PBLK) {
        const int eb = blockIdx.x * EPB;
        for (int i = tid; i < NBUCK; i += 256) sh[i] = 0;
        __syncthreads();

        unsigned val[EPT], bk[EPT];
#pragma unroll
        for (int l = 0; l < EPT; ++l) {
            int e = eb + l * 256 + tid;
            unsigned src = (unsigned)ei[e];
            unsigned dst = (unsigned)ei[NE + e];
            val[l] = (src << 6) | (dst & 63u);
            bk[l] = dst >> 6;
            atomicAdd(&sh[bk[l]], 1u);
        }
        __syncthreads();

        for (int i = tid; i < NBUCK; i += 256) {
            unsigned h = sh[i];
            sb[i] = (unsigned)i * SLOT + (h ? atomicAdd(&gcur[i], h) : 0u);
            sc[i] = 0;
        }
        __syncthreads();

#pragma unroll
        for (int l = 0; l < EPT; ++l) {
            unsigned b = bk[l];
            unsigned pos = sb[b] + atomicAdd(&sc[b], 1u);
            if (pos < (b + 1u) * SLOT) pairs[pos] = val[l];   // overflow guard
        }
        return;
    }

    int i = (blockIdx.x - PBLK) * 256 + tid;
    if (i < WTE_N) {
        int j = i & 7, lane = (i >> 3) & 63, cf = (i >> 9) & 7, ch = i >> 12;
        int k = ch * 32 + (lane >> 4) * 8 + j;
        int n = cf * 16 + (lane & 15);
        wte[i] = f2bf((k < KE) ? We[k * DD + n] : 0.f);
    } else if (i < WTE_N + WTG_N) {
        int t = i - WTE_N;
        int j = t & 7, lane = (t >> 3) & 63, cf = (t >> 9) & 7, ks = t >> 12;
        int k = ks * 32 + (lane >> 4) * 8 + j;
        int n = cf * 16 + (lane & 15);
        wtg[t] = f2bf(Wg[k * DD + n]);
    }
}

// ---------------- encoder: weights-stationary persistent GEMM ---------------
// All 80 B fragments resident in VGPRs (320 regs) for the kernel lifetime;
// 1 wave/SIMD (__launch_bounds__(256,1)). Per 64-row tile: 10 independent A
// loads + 80 MFMAs, no LDS, no barriers, B never reloaded.
__global__ __launch_bounds__(256, 1) void enc_mfma(const float* __restrict__ x,
                                                   const ushort_t* __restrict__ wtF,
                                                   ushort_t* __restrict__ news) {
    const int tid = threadIdx.x;
    const int w = tid >> 6, lane = tid & 63;
    const int hl = lane & 15, kg = lane >> 4;

    bf16x8 B[10][8];
#pragma unroll
    for (int c = 0; c < 10; ++c)
#pragma unroll
        for (int cf = 0; cf < 8; ++cf)
            B[c][cf] = *(const bf16x8*)&wtF[(c * 8 + cf) * 512 + lane * 8];

    for (int tile = blockIdx.x; tile < EBLK; tile += gridDim.x) {
        const int row0 = tile * 64 + w * 16;
        const int r0 = row0 + hl;
        const bool ok0 = r0 < NN;
        const float* xr = &x[(long long)r0 * KE + kg * 8];
        const float4 fz = make_float4(0.f, 0.f, 0.f, 0.f);

        // phase 1: all raw A loads (independent, deep MLP)
        float4 ra[9][2];
        if (ok0) {
#pragma unroll
            for (int c = 0; c < 9; ++c) {
                const float4* p = (const float4*)(xr + c * 32);
                ra[c][0] = p[0];
                ra[c][1] = p[1];
            }
        } else {
#pragma unroll
            for (int c = 0; c < 9; ++c) { ra[c][0] = fz; ra[c][1] = fz; }
        }
        bf16x8 a9 = loadA8m(x, r0, 288 + kg * 8, ok0);

        f32x4 acc[8];
#pragma unroll
        for (int j = 0; j < 8; ++j) acc[j] = (f32x4)0.f;

        // phase 2: MFMA sweep against resident B
#pragma unroll
        for (int c = 0; c < 9; ++c) {
            bf16x8 a = pack8(ra[c][0], ra[c][1]);
#pragma unroll
            for (int cf = 0; cf < 8; ++cf)
                acc[cf] = __builtin_amdgcn_mfma_f32_16x16x32_bf16(a, B[c][cf], acc[cf], 0, 0, 0);
        }
#pragma unroll
        for (int cf = 0; cf < 8; ++cf)
            acc[cf] = __builtin_amdgcn_mfma_f32_16x16x32_bf16(a9, B[9][cf], acc[cf], 0, 0, 0);

#pragma unroll
        for (int cf = 0; cf < 8; ++cf)
#pragma unroll
            for (int j = 0; j < 4; ++j) {
                int grow = row0 + kg * 4 + j;
                int gcol = cf * 16 + hl;
                if (grow < NN)
                    news[(long long)grow * DD + gcol] = f2bf(acc[cf][j]);
            }
    }
}

// ------- fused bucket aggregate + GNN GEMM + epilogue (512 threads) ---------
// Phase A: 64-dst LDS CSR + register gather (8 waves -> 2x edges in flight),
// agg rows kept in LDS (bf16, chunk-XOR swizzle). Phase B: 8 waves split as
// 4 row-groups x 2 cf-halves MFMA vs wt_gnn + residual epilogue.
__global__ __launch_bounds__(512) void k_baggnn(const unsigned* __restrict__ gcur,
                                                const unsigned* __restrict__ pairs,
                                                const ushort_t* __restrict__ news,
                                                const ushort_t* __restrict__ wtF,
                                                float* __restrict__ xx) {
    __shared__ unsigned srcs[SLOT];
    __shared__ unsigned hist[64], base[64], cur[64];
    __shared__ ushort_t aggs[64 * DD];         // 16 KB, swizzled 16B chunks
    const int tid = threadIdx.x;
    const int b = blockIdx.x;
    int cnt = (int)gcur[b];
    if (cnt > SLOT) cnt = SLOT;

    if (tid < 64) hist[tid] = 0;
    __syncthreads();
    for (int i = tid; i < cnt; i += 512)
        atomicAdd(&hist[pairs[b * SLOT + i] & 63u], 1u);
    __syncthreads();

    // single-wave exclusive scan of 64 bins
    if (tid < 64) {
        unsigned h = hist[tid], v = h;
#pragma unroll
        for (int off = 1; off < 64; off <<= 1) {
            unsigned n = __shfl_up(v, off);
            if (tid >= off) v += n;
        }
        base[tid] = v - h;
        cur[tid]  = v - h;
    }
    __syncthreads();

    for (int i = tid; i < cnt; i += 512) {
        unsigned v = pairs[b * SLOT + i];
        srcs[atomicAdd(&cur[v & 63u], 1u)] = v >> 6;
    }
    __syncthreads();

    // ---- phase A: wave per dst (8 waves), 4 edge slots, depth-2 pipeline ---
    const int w = tid >> 6, lane = tid & 63;
    const int e = lane >> 4, l = lane & 15;
    for (int d = w; d < 64; d += 8) {
        int gd = b * 64 + d;
        if (gd >= NN) break;                 // uniform per wave
        int s0 = (int)base[d], c = (int)hist[d];
        float acc[8];
#pragma unroll
        for (int j = 0; j < 8; ++j) acc[j] = 0.f;

        uint4 v = make_uint4(0u, 0u, 0u, 0u);
        if (e < c)
            v = *(const uint4*)&news[(long long)srcs[s0 + e] * DD + l * 8];
        for (int i = 4; i < c; i += 4) {
            uint4 vn = make_uint4(0u, 0u, 0u, 0u);
            int ii = i + e;
            if (ii < c)
                vn = *(const uint4*)&news[(long long)srcs[s0 + ii] * DD + l * 8];
            acc[0] += bf2f(v.x & 0xFFFFu); acc[1] += bf2f(v.x >> 16);
            acc[2] += bf2f(v.y & 0xFFFFu); acc[3] += bf2f(v.y >> 16);
            acc[4] += bf2f(v.z & 0xFFFFu); acc[5] += bf2f(v.z >> 16);
            acc[6] += bf2f(v.w & 0xFFFFu); acc[7] += bf2f(v.w >> 16);
            v = vn;
        }
        acc[0] += bf2f(v.x & 0xFFFFu); acc[1] += bf2f(v.x >> 16);
        acc[2] += bf2f(v.y & 0xFFFFu); acc[3] += bf2f(v.y >> 16);
        acc[4] += bf2f(v.z & 0xFFFFu); acc[5] += bf2f(v.z >> 16);
        acc[6] += bf2f(v.w & 0xFFFFu); acc[7] += bf2f(v.w >> 16);

#pragma unroll
        for (int j = 0; j < 8; ++j) {
            acc[j] += __shfl_xor(acc[j], 16);
            acc[j] += __shfl_xor(acc[j], 32);
        }
        if (e == 0) {
            uint4 o;
            o.x = (unsigned)f2bf(acc[0]) | ((unsigned)f2bf(acc[1]) << 16);
            o.y = (unsigned)f2bf(acc[2]) | ((unsigned)f2bf(acc[3]) << 16);
            o.z = (unsigned)f2bf(acc[4]) | ((unsigned)f2bf(acc[5]) << 16);
            o.w = (unsigned)f2bf(acc[6]) | ((unsigned)f2bf(acc[7]) << 16);
            *(uint4*)&aggs[d * DD + (l ^ (d & 15)) * 8] = o;   // swizzled chunk
        }
    }
    __syncthreads();

    // ---- phase B: gnn MFMA; wave w -> rows (w&3)*16, cf half (w>>2)*4 ----
    const int hl = lane & 15, kg = lane >> 4;
    const int rw = (w & 3) * 16;
    const int cfb = (w >> 2) * 4;
    U4B a[4];
#pragma unroll
    for (int ks = 0; ks < 4; ++ks)
        a[ks].u = *(const uint4*)&aggs[(rw + hl) * DD + ((ks * 4 + kg) ^ hl) * 8];

    f32x4 acc[4];
#pragma unroll
    for (int j = 0; j < 4; ++j) acc[j] = (f32x4)0.f;

#pragma unroll
    for (int ks = 0; ks < 4; ++ks) {
        const ushort_t* bp = &wtF[(ks * 8 + cfb) * 512 + lane * 8];
#pragma unroll
        for (int cf = 0; cf < 4; ++cf) {
            bf16x8 bfr = *(const bf16x8*)&bp[cf * 512];
            acc[cf] = __builtin_amdgcn_mfma_f32_16x16x32_bf16(a[ks].b, bfr, acc[cf], 0, 0, 0);
        }
    }

#pragma unroll
    for (int j = 0; j < 4; ++j) {
        int lr = rw + kg * 4 + j;
        int grow = b * 64 + lr;
        if (grow < NN) {
            float s = 1.f / fmaxf((float)hist[lr], 1.f);
#pragma unroll
            for (int cf = 0; cf < 4; ++cf) {
                int gcol = (cfb + cf) * 16 + hl;
                float nv = bf2f((unsigned)news[(long long)grow * DD + gcol]);
                xx[(long long)grow * DD + gcol] = nv + acc[cf][j] * s;
            }
        }
    }
}

// ---------------- fused user vector + scores --------------------------------
__global__ __launch_bounds__(128) void k_user(const int* __restrict__ hist,
                                              const int* __restrict__ cand,
                                              const float* __restrict__ xx,
                                              float* __restrict__ out) {
    __shared__ float uvs[128];
    const int b = blockIdx.x, t = threadIdx.x;

    float s = 0.f, cnt = 0.f;
    for (int h = 0; h < HL; ++h) {
        int id = hist[b * HL + h];
        if (id != 0) { s += xx[(long long)id * DD + t]; cnt += 1.f; }
    }
    uvs[t] = s / fmaxf(cnt, 1e-9f);
    __syncthreads();

    const int w = t >> 6, lane = t & 63;
    float2 uvp = *(const float2*)&uvs[lane * 2];
    for (int c = w; c < CL; c += 2) {
        int id = cand[b * CL + c];
        float2 xv = *(const float2*)&xx[(long long)id * DD + lane * 2];
        float p = uvp.x * xv.x + uvp.y * xv.y;
#pragma unroll
        for (int off = 32; off >= 1; off >>= 1) p += __shfl_xor(p, off);
        if (lane == 0) out[b * CL + c] = p;
    }
}

extern "C" void kernel_launch(void* const* d_in, const int* in_sizes, int n_in,
                              void* d_out, int out_size, void* d_ws, size_t ws_size,
                              hipStream_t stream) {
    const float* x    = (const float*)d_in[0];
    // d_in[1] = n_id == arange(N) -> identity scatter, unused
    const int*   ei   = (const int*)d_in[2];
    const int*   hist = (const int*)d_in[3];
    const int*   cand = (const int*)d_in[4];
    const float* Wenc = (const float*)d_in[5];
    const float* Wgnn = (const float*)d_in[6];
    float* out = (float*)d_out;

    float*    xx      = (float*)d_ws;                      // [NN*DD] f32
    ushort_t* news_bf = (ushort_t*)(xx + (size_t)NN * DD); // [NN*DD] bf16
    ushort_t* wt_enc  = news_bf + (size_t)NN * DD;         // [WTE_N]
    ushort_t* wt_gnn  = wt_enc + WTE_N;                    // [WTG_N]
    unsigned* gcur    = (unsigned*)(wt_gnn + WTG_N);       // [NBUCK]
    unsigned* pairs   = gcur + NBUCK;                      // [NBUCK*SLOT]

    hipMemsetAsync(gcur, 0, NBUCK * sizeof(unsigned), stream);

    k_prep<<<PBLK + PREPB, 256, 0, stream>>>(ei, gcur, pairs, Wenc, Wgnn, wt_enc, wt_gnn);
    enc_mfma<<<256, 256, 0, stream>>>(x, wt_enc, news_bf);
    k_baggnn<<<NBUCK, 512, 0, stream>>>(gcur, pairs, news_bf, wt_gnn, xx);
    k_user<<<NB, 128, 0, stream>>>(hist, cand, xx, out);
}

// Round 14
// 164.594 us; speedup vs baseline: 1.4746x; 1.0293x over previous
//
#include <hip/hip_runtime.h>

#define NN 100000      // nodes
#define DD 128         // embedding dim
#define KE 300         // raw feature dim
#define NE 1600000     // edges
#define NB 4096        // batch (users)
#define HL 50          // history length
#define CL 20          // candidates

#define NBUCK 1563     // ceil(NN/64): buckets of 64 dst nodes
#define SLOT  1280     // max edges/bucket (mean 1024, sigma 32, +8 sigma)
#define PBLK  250      // partition blocks
#define EPB   6400     // edges per partition block
#define EPT   25       // edges per thread
#define EBLK  1563     // enc row-tiles (64 rows each)

#define WTE_N 40960    // 128 cols x 320 k, fragment-major
#define WTG_N 16384    // 128 cols x 128 k, fragment-major
#define PREPB ((WTE_N + WTG_N + 255) / 256)   // 224 weight-prep blocks

typedef unsigned short ushort_t;
using bf16x8 = __attribute__((ext_vector_type(8))) short;
using f32x4  = __attribute__((ext_vector_type(4))) float;

union U4B { uint4 u; bf16x8 b; unsigned a[4]; };

__device__ __forceinline__ ushort_t f2bf(float f) {
    unsigned u = __float_as_uint(f);
    unsigned r = u + 0x7FFF + ((u >> 16) & 1);   // RNE
    return (ushort_t)(r >> 16);
}
__device__ __forceinline__ float bf2f(unsigned s) {
    return __uint_as_float(s << 16);
}
__device__ __forceinline__ bf16x8 pack8(float4 a, float4 b) {
    U4B r;
    r.a[0] = (unsigned)f2bf(a.x) | ((unsigned)f2bf(a.y) << 16);
    r.a[1] = (unsigned)f2bf(a.z) | ((unsigned)f2bf(a.w) << 16);
    r.a[2] = (unsigned)f2bf(b.x) | ((unsigned)f2bf(b.y) << 16);
    r.a[3] = (unsigned)f2bf(b.z) | ((unsigned)f2bf(b.w) << 16);
    return r.b;
}

// ---- masked A fragment loader (tail chunk crossing KE) ---------------------
__device__ __forceinline__ bf16x8 loadA8m(const float* __restrict__ x,
                                          int row, int col, bool rowok) {
    float v[8];
#pragma unroll
    for (int j = 0; j < 8; ++j) {
        int c = col + j;
        v[j] = (rowok && c < KE) ? x[(long long)row * KE + c] : 0.f;
    }
    return pack8(make_float4(v[0], v[1], v[2], v[3]),
                 make_float4(v[4], v[5], v[6], v[7]));
}

// ------- fused prep: edge partition (blocks < PBLK) + weight transpose ------
// wtF[((chunk*8+cf)*64 + lane)*8 + j] = W[k][n],
//   k = chunk*32 + (lane>>4)*8 + j,  n = cf*16 + (lane&15).
__global__ __launch_bounds__(256) void k_prep(const int* __restrict__ ei,
                                              unsigned* __restrict__ gcur,
                                              unsigned* __restrict__ pairs,
                                              const float* __restrict__ We,
                                              const float* __restrict__ Wg,
                                              ushort_t* __restrict__ wte,
                                              ushort_t* __restrict__ wtg) {
    __shared__ unsigned sh[NBUCK], sb[NBUCK], sc[NBUCK];
    const int tid = threadIdx.x;

    if (blockIdx.x < PBLK) {
        const int eb = blockIdx.x * EPB;
        for (int i = tid; i < NBUCK; i += 256) sh[i] = 0;
        __syncthreads();

        unsigned val[EPT], bk[EPT];
#pragma unroll
        for (int l = 0; l < EPT; ++l) {
            int e = eb + l * 256 + tid;
            unsigned src = (unsigned)ei[e];
            unsigned dst = (unsigned)ei[NE + e];
            val[l] = (src << 6) | (dst & 63u);
            bk[l] = dst >> 6;
            atomicAdd(&sh[bk[l]], 1u);
        }
        __syncthreads();

        for (int i = tid; i < NBUCK; i += 256) {
            unsigned h = sh[i];
            sb[i] = (unsigned)i * SLOT + (h ? atomicAdd(&gcur[i], h) : 0u);
            sc[i] = 0;
        }
        __syncthreads();

#pragma unroll
        for (int l = 0; l < EPT; ++l) {
            unsigned b = bk[l];
            unsigned pos = sb[b] + atomicAdd(&sc[b], 1u);
            if (pos < (b + 1u) * SLOT) pairs[pos] = val[l];   // overflow guard
        }
        return;
    }

    int i = (blockIdx.x - PBLK) * 256 + tid;
    if (i < WTE_N) {
        int j = i & 7, lane = (i >> 3) & 63, cf = (i >> 9) & 7, ch = i >> 12;
        int k = ch * 32 + (lane >> 4) * 8 + j;
        int n = cf * 16 + (lane & 15);
        wte[i] = f2bf((k < KE) ? We[k * DD + n] : 0.f);
    } else if (i < WTE_N + WTG_N) {
        int t = i - WTE_N;
        int j = t & 7, lane = (t >> 3) & 63, cf = (t >> 9) & 7, ks = t >> 12;
        int k = ks * 32 + (lane >> 4) * 8 + j;
        int n = cf * 16 + (lane & 15);
        wtg[t] = f2bf(Wg[k * DD + n]);
    }
}

// ---------------- encoder: weights-stationary persistent GEMM ---------------
// All 80 B fragments resident in VGPRs; 1 wave/SIMD. Per 64-row tile: 10
// independent A loads + 80 MFMAs, no LDS, no barriers, B never reloaded.
__global__ __launch_bounds__(256, 1) void enc_mfma(const float* __restrict__ x,
                                                   const ushort_t* __restrict__ wtF,
                                                   ushort_t* __restrict__ news) {
    const int tid = threadIdx.x;
    const int w = tid >> 6, lane = tid & 63;
    const int hl = lane & 15, kg = lane >> 4;

    bf16x8 B[10][8];
#pragma unroll
    for (int c = 0; c < 10; ++c)
#pragma unroll
        for (int cf = 0; cf < 8; ++cf)
            B[c][cf] = *(const bf16x8*)&wtF[(c * 8 + cf) * 512 + lane * 8];

    for (int tile = blockIdx.x; tile < EBLK; tile += gridDim.x) {
        const int row0 = tile * 64 + w * 16;
        const int r0 = row0 + hl;
        const bool ok0 = r0 < NN;
        const float* xr = &x[(long long)r0 * KE + kg * 8];
        const float4 fz = make_float4(0.f, 0.f, 0.f, 0.f);

        float4 ra[9][2];
        if (ok0) {
#pragma unroll
            for (int c = 0; c < 9; ++c) {
                const float4* p = (const float4*)(xr + c * 32);
                ra[c][0] = p[0];
                ra[c][1] = p[1];
            }
        } else {
#pragma unroll
            for (int c = 0; c < 9; ++c) { ra[c][0] = fz; ra[c][1] = fz; }
        }
        bf16x8 a9 = loadA8m(x, r0, 288 + kg * 8, ok0);

        f32x4 acc[8];
#pragma unroll
        for (int j = 0; j < 8; ++j) acc[j] = (f32x4)0.f;

#pragma unroll
        for (int c = 0; c < 9; ++c) {
            bf16x8 a = pack8(ra[c][0], ra[c][1]);
#pragma unroll
            for (int cf = 0; cf < 8; ++cf)
                acc[cf] = __builtin_amdgcn_mfma_f32_16x16x32_bf16(a, B[c][cf], acc[cf], 0, 0, 0);
        }
#pragma unroll
        for (int cf = 0; cf < 8; ++cf)
            acc[cf] = __builtin_amdgcn_mfma_f32_16x16x32_bf16(a9, B[9][cf], acc[cf], 0, 0, 0);

#pragma unroll
        for (int cf = 0; cf < 8; ++cf)
#pragma unroll
            for (int j = 0; j < 4; ++j) {
                int grow = row0 + kg * 4 + j;
                int gcol = cf * 16 + hl;
                if (grow < NN)
                    news[(long long)grow * DD + gcol] = f2bf(acc[cf][j]);
            }
    }
}

// ------- fused bucket aggregate + GNN GEMM + epilogue (512 threads) ---------
// Phase A: 64-dst LDS CSR + register gather; agg rows in LDS (bf16, chunk-XOR
// swizzle). Phase B: 8 waves = 4 row-groups x 2 cf-halves MFMA + residual.
// xx output is bf16 (consumed only by gathers in k_user).
__global__ __launch_bounds__(512) void k_baggnn(const unsigned* __restrict__ gcur,
                                                const unsigned* __restrict__ pairs,
                                                const ushort_t* __restrict__ news,
                                                const ushort_t* __restrict__ wtF,
                                                ushort_t* __restrict__ xxb) {
    __shared__ unsigned srcs[SLOT];
    __shared__ unsigned hist[64], base[64], cur[64];
    __shared__ ushort_t aggs[64 * DD];         // 16 KB, swizzled 16B chunks
    const int tid = threadIdx.x;
    const int b = blockIdx.x;
    int cnt = (int)gcur[b];
    if (cnt > SLOT) cnt = SLOT;

    if (tid < 64) hist[tid] = 0;
    __syncthreads();
    for (int i = tid; i < cnt; i += 512)
        atomicAdd(&hist[pairs[b * SLOT + i] & 63u], 1u);
    __syncthreads();

    // single-wave exclusive scan of 64 bins
    if (tid < 64) {
        unsigned h = hist[tid], v = h;
#pragma unroll
        for (int off = 1; off < 64; off <<= 1) {
            unsigned n = __shfl_up(v, off);
            if (tid >= off) v += n;
        }
        base[tid] = v - h;
        cur[tid]  = v - h;
    }
    __syncthreads();

    for (int i = tid; i < cnt; i += 512) {
        unsigned v = pairs[b * SLOT + i];
        srcs[atomicAdd(&cur[v & 63u], 1u)] = v >> 6;
    }
    __syncthreads();

    // ---- phase A: wave per dst (8 waves), 4 edge slots, depth-2 pipeline ---
    const int w = tid >> 6, lane = tid & 63;
    const int e = lane >> 4, l = lane & 15;
    for (int d = w; d < 64; d += 8) {
        int gd = b * 64 + d;
        if (gd >= NN) break;                 // uniform per wave
        int s0 = (int)base[d], c = (int)hist[d];
        float acc[8];
#pragma unroll
        for (int j = 0; j < 8; ++j) acc[j] = 0.f;

        uint4 v = make_uint4(0u, 0u, 0u, 0u);
        if (e < c)
            v = *(const uint4*)&news[(long long)srcs[s0 + e] * DD + l * 8];
        for (int i = 4; i < c; i += 4) {
            uint4 vn = make_uint4(0u, 0u, 0u, 0u);
            int ii = i + e;
            if (ii < c)
                vn = *(const uint4*)&news[(long long)srcs[s0 + ii] * DD + l * 8];
            acc[0] += bf2f(v.x & 0xFFFFu); acc[1] += bf2f(v.x >> 16);
            acc[2] += bf2f(v.y & 0xFFFFu); acc[3] += bf2f(v.y >> 16);
            acc[4] += bf2f(v.z & 0xFFFFu); acc[5] += bf2f(v.z >> 16);
            acc[6] += bf2f(v.w & 0xFFFFu); acc[7] += bf2f(v.w >> 16);
            v = vn;
        }
        acc[0] += bf2f(v.x & 0xFFFFu); acc[1] += bf2f(v.x >> 16);
        acc[2] += bf2f(v.y & 0xFFFFu); acc[3] += bf2f(v.y >> 16);
        acc[4] += bf2f(v.z & 0xFFFFu); acc[5] += bf2f(v.z >> 16);
        acc[6] += bf2f(v.w & 0xFFFFu); acc[7] += bf2f(v.w >> 16);

#pragma unroll
        for (int j = 0; j < 8; ++j) {
            acc[j] += __shfl_xor(acc[j], 16);
            acc[j] += __shfl_xor(acc[j], 32);
        }
        if (e == 0) {
            uint4 o;
            o.x = (unsigned)f2bf(acc[0]) | ((unsigned)f2bf(acc[1]) << 16);
            o.y = (unsigned)f2bf(acc[2]) | ((unsigned)f2bf(acc[3]) << 16);
            o.z = (unsigned)f2bf(acc[4]) | ((unsigned)f2bf(acc[5]) << 16);
            o.w = (unsigned)f2bf(acc[6]) | ((unsigned)f2bf(acc[7]) << 16);
            *(uint4*)&aggs[d * DD + (l ^ (d & 15)) * 8] = o;   // swizzled chunk
        }
    }
    __syncthreads();

    // ---- phase B: gnn MFMA; wave w -> rows (w&3)*16, cf half (w>>2)*4 ----
    const int hl = lane & 15, kg = lane >> 4;
    const int rw = (w & 3) * 16;
    const int cfb = (w >> 2) * 4;
    U4B a[4];
#pragma unroll
    for (int ks = 0; ks < 4; ++ks)
        a[ks].u = *(const uint4*)&aggs[(rw + hl) * DD + ((ks * 4 + kg) ^ hl) * 8];

    f32x4 acc[4];
#pragma unroll
    for (int j = 0; j < 4; ++j) acc[j] = (f32x4)0.f;

#pragma unroll
    for (int ks = 0; ks < 4; ++ks) {
        const ushort_t* bp = &wtF[(ks * 8 + cfb) * 512 + lane * 8];
#pragma unroll
        for (int cf = 0; cf < 4; ++cf) {
            bf16x8 bfr = *(const bf16x8*)&bp[cf * 512];
            acc[cf] = __builtin_amdgcn_mfma_f32_16x16x32_bf16(a[ks].b, bfr, acc[cf], 0, 0, 0);
        }
    }

#pragma unroll
    for (int j = 0; j < 4; ++j) {
        int lr = rw + kg * 4 + j;
        int grow = b * 64 + lr;
        if (grow < NN) {
            float s = 1.f / fmaxf((float)hist[lr], 1.f);
#pragma unroll
            for (int cf = 0; cf < 4; ++cf) {
                int gcol = (cfb + cf) * 16 + hl;
                float nv = bf2f((unsigned)news[(long long)grow * DD + gcol]);
                xxb[(long long)grow * DD + gcol] = f2bf(nv + acc[cf][j] * s);
            }
        }
    }
}

// ---------------- fused user vector + scores (bf16 xx gathers) --------------
// 2 waves: wave w handles history rows h = w, w+2, ... then candidates
// c = w, w+2, ...  Each 64-lane wave reads a 256B bf16 row as uint per lane.
__global__ __launch_bounds__(128) void k_user(const int* __restrict__ hist,
                                              const int* __restrict__ cand,
                                              const ushort_t* __restrict__ xxb,
                                              float* __restrict__ out) {
    __shared__ float part[2][128];
    __shared__ float cnts[2];
    __shared__ float uvs[128];
    const int b = blockIdx.x, t = threadIdx.x;
    const int w = t >> 6, lane = t & 63;

    float s0 = 0.f, s1 = 0.f, cnt = 0.f;
    for (int h = w; h < HL; h += 2) {
        int id = hist[b * HL + h];
        if (id != 0) {
            unsigned v = *(const unsigned*)&xxb[(long long)id * DD + lane * 2];
            s0 += bf2f(v & 0xFFFFu);
            s1 += bf2f(v >> 16);
            cnt += 1.f;
        }
    }
    part[w][lane * 2]     = s0;
    part[w][lane * 2 + 1] = s1;
    if (lane == 0) cnts[w] = cnt;
    __syncthreads();

    float inv = 1.f / fmaxf(cnts[0] + cnts[1], 1e-9f);
    uvs[t] = (part[0][t] + part[1][t]) * inv;
    __syncthreads();

    float2 uvp = *(const float2*)&uvs[lane * 2];
    for (int c = w; c < CL; c += 2) {
        int id = cand[b * CL + c];
        unsigned v = *(const unsigned*)&xxb[(long long)id * DD + lane * 2];
        float p = uvp.x * bf2f(v & 0xFFFFu) + uvp.y * bf2f(v >> 16);
#pragma unroll
        for (int off = 32; off >= 1; off >>= 1) p += __shfl_xor(p, off);
        if (lane == 0) out[b * CL + c] = p;
    }
}

extern "C" void kernel_launch(void* const* d_in, const int* in_sizes, int n_in,
                              void* d_out, int out_size, void* d_ws, size_t ws_size,
                              hipStream_t stream) {
    const float* x    = (const float*)d_in[0];
    // d_in[1] = n_id == arange(N) -> identity scatter, unused
    const int*   ei   = (const int*)d_in[2];
    const int*   hist = (const int*)d_in[3];
    const int*   cand = (const int*)d_in[4];
    const float* Wenc = (const float*)d_in[5];
    const float* Wgnn = (const float*)d_in[6];
    float* out = (float*)d_out;

    ushort_t* news_bf = (ushort_t*)d_ws;                   // [NN*DD] bf16
    ushort_t* xx_bf   = news_bf + (size_t)NN * DD;         // [NN*DD] bf16
    ushort_t* wt_enc  = xx_bf + (size_t)NN * DD;           // [WTE_N]
    ushort_t* wt_gnn  = wt_enc + WTE_N;                    // [WTG_N]
    unsigned* gcur    = (unsigned*)(wt_gnn + WTG_N);       // [NBUCK]
    unsigned* pairs   = gcur + NBUCK;                      // [NBUCK*SLOT]

    hipMemsetAsync(gcur, 0, NBUCK * sizeof(unsigned), stream);

    k_prep<<<PBLK + PREPB, 256, 0, stream>>>(ei, gcur, pairs, Wenc, Wgnn, wt_enc, wt_gnn);
    enc_mfma<<<256, 256, 0, stream>>>(x, wt_enc, news_bf);
    k_baggnn<<<NBUCK, 512, 0, stream>>>(gcur, pairs, news_bf, wt_gnn, xx_bf);
    k_user<<<NB, 128, 0, stream>>>(hist, cand, xx_bf, out);
}

// Round 15
// 153.557 us; speedup vs baseline: 1.5806x; 1.0719x over previous
//
#include <hip/hip_runtime.h>

#define NN 100000      // nodes
#define DD 128         // embedding dim
#define KE 300         // raw feature dim
#define NE 1600000     // edges
#define NB 4096        // batch (users)
#define HL 50          // history length
#define CL 20          // candidates

#define NBUCK 1563     // ceil(NN/64): buckets of 64 dst nodes
#define SLOT  1280     // max edges/bucket (mean 1024, sigma 32, +8 sigma)
#define PBLK  250      // partition blocks
#define EPB   6400     // edges per partition block
#define EPT   25       // edges per thread
#define EBLK  1563     // enc row-tiles (64 rows each)

#define WTE_N 40960    // 128 cols x 320 k, fragment-major
#define WTG_N 16384    // 128 cols x 128 k, fragment-major
#define PREPB ((WTE_N + WTG_N + 255) / 256)   // 224 weight-prep blocks

typedef unsigned short ushort_t;
typedef unsigned char uchar_t;
using bf16x8 = __attribute__((ext_vector_type(8))) short;
using f32x4  = __attribute__((ext_vector_type(4))) float;
using v2f    = __attribute__((ext_vector_type(2))) float;

union U4B { uint4 u; bf16x8 b; unsigned a[4]; };

__device__ __forceinline__ ushort_t f2bf(float f) {
    unsigned u = __float_as_uint(f);
    unsigned r = u + 0x7FFF + ((u >> 16) & 1);   // RNE
    return (ushort_t)(r >> 16);
}
__device__ __forceinline__ float bf2f(unsigned s) {
    return __uint_as_float(s << 16);
}
__device__ __forceinline__ bf16x8 pack8(float4 a, float4 b) {
    U4B r;
    r.a[0] = (unsigned)f2bf(a.x) | ((unsigned)f2bf(a.y) << 16);
    r.a[1] = (unsigned)f2bf(a.z) | ((unsigned)f2bf(a.w) << 16);
    r.a[2] = (unsigned)f2bf(b.x) | ((unsigned)f2bf(b.y) << 16);
    r.a[3] = (unsigned)f2bf(b.z) | ((unsigned)f2bf(b.w) << 16);
    return r.b;
}

// ---- masked A fragment loader (tail chunk crossing KE) ---------------------
__device__ __forceinline__ bf16x8 loadA8m(const float* __restrict__ x,
                                          int row, int col, bool rowok) {
    float v[8];
#pragma unroll
    for (int j = 0; j < 8; ++j) {
        int c = col + j;
        v[j] = (rowok && c < KE) ? x[(long long)row * KE + c] : 0.f;
    }
    return pack8(make_float4(v[0], v[1], v[2], v[3]),
                 make_float4(v[4], v[5], v[6], v[7]));
}

// ------- fused prep: edge partition (blocks < PBLK) + weight transpose ------
// wtF[((chunk*8+cf)*64 + lane)*8 + j] = W[k][n],
//   k = chunk*32 + (lane>>4)*8 + j,  n = cf*16 + (lane&15).
__global__ __launch_bounds__(256) void k_prep(const int* __restrict__ ei,
                                              unsigned* __restrict__ gcur,
                                              unsigned* __restrict__ pairs,
                                              const float* __restrict__ We,
                                              const float* __restrict__ Wg,
                                              ushort_t* __restrict__ wte,
                                              ushort_t* __restrict__ wtg) {
    __shared__ unsigned sh[NBUCK], sb[NBUCK], sc[NBUCK];
    const int tid = threadIdx.x;

    if (blockIdx.x < PBLK) {
        const int eb = blockIdx.x * EPB;
        for (int i = tid; i < NBUCK; i += 256) sh[i] = 0;
        __syncthreads();

        unsigned val[EPT], bk[EPT];
#pragma unroll
        for (int l = 0; l < EPT; ++l) {
            int e = eb + l * 256 + tid;
            unsigned src = (unsigned)ei[e];
            unsigned dst = (unsigned)ei[NE + e];
            val[l] = (src << 6) | (dst & 63u);
            bk[l] = dst >> 6;
            atomicAdd(&sh[bk[l]], 1u);
        }
        __syncthreads();

        for (int i = tid; i < NBUCK; i += 256) {
            unsigned h = sh[i];
            sb[i] = (unsigned)i * SLOT + (h ? atomicAdd(&gcur[i], h) : 0u);
            sc[i] = 0;
        }
        __syncthreads();

#pragma unroll
        for (int l = 0; l < EPT; ++l) {
            unsigned b = bk[l];
            unsigned pos = sb[b] + atomicAdd(&sc[b], 1u);
            if (pos < (b + 1u) * SLOT) pairs[pos] = val[l];   // overflow guard
        }
        return;
    }

    int i = (blockIdx.x - PBLK) * 256 + tid;
    if (i < WTE_N) {
        int j = i & 7, lane = (i >> 3) & 63, cf = (i >> 9) & 7, ch = i >> 12;
        int k = ch * 32 + (lane >> 4) * 8 + j;
        int n = cf * 16 + (lane & 15);
        wte[i] = f2bf((k < KE) ? We[k * DD + n] : 0.f);
    } else if (i < WTE_N + WTG_N) {
        int t = i - WTE_N;
        int j = t & 7, lane = (t >> 3) & 63, cf = (t >> 9) & 7, ks = t >> 12;
        int k = ks * 32 + (lane >> 4) * 8 + j;
        int n = cf * 16 + (lane & 15);
        wtg[t] = f2bf(Wg[k * DD + n]);
    }
}

// ---------------- encoder: weights-stationary persistent GEMM ---------------
// All 80 B fragments resident in VGPRs; per 64-row tile: 10 independent A
// loads + 80 MFMAs, B never reloaded. Emits news in bf16 AND an fp8-e4m3
// sidecar (LDS-staged for coalesced 32B/thread stores).
__global__ __launch_bounds__(256, 1) void enc_mfma(const float* __restrict__ x,
                                                   const ushort_t* __restrict__ wtF,
                                                   ushort_t* __restrict__ news,
                                                   uchar_t* __restrict__ nf8) {
    __shared__ uchar_t f8s[64 * DD];           // 8 KB fp8 staging tile
    const int tid = threadIdx.x;
    const int w = tid >> 6, lane = tid & 63;
    const int hl = lane & 15, kg = lane >> 4;

    bf16x8 B[10][8];
#pragma unroll
    for (int c = 0; c < 10; ++c)
#pragma unroll
        for (int cf = 0; cf < 8; ++cf)
            B[c][cf] = *(const bf16x8*)&wtF[(c * 8 + cf) * 512 + lane * 8];

    for (int tile = blockIdx.x; tile < EBLK; tile += gridDim.x) {
        const int row0 = tile * 64 + w * 16;
        const int r0 = row0 + hl;
        const bool ok0 = r0 < NN;
        const float* xr = &x[(long long)r0 * KE + kg * 8];
        const float4 fz = make_float4(0.f, 0.f, 0.f, 0.f);

        float4 ra[9][2];
        if (ok0) {
#pragma unroll
            for (int c = 0; c < 9; ++c) {
                const float4* p = (const float4*)(xr + c * 32);
                ra[c][0] = p[0];
                ra[c][1] = p[1];
            }
        } else {
#pragma unroll
            for (int c = 0; c < 9; ++c) { ra[c][0] = fz; ra[c][1] = fz; }
        }
        bf16x8 a9 = loadA8m(x, r0, 288 + kg * 8, ok0);

        f32x4 acc[8];
#pragma unroll
        for (int j = 0; j < 8; ++j) acc[j] = (f32x4)0.f;

#pragma unroll
        for (int c = 0; c < 9; ++c) {
            bf16x8 a = pack8(ra[c][0], ra[c][1]);
#pragma unroll
            for (int cf = 0; cf < 8; ++cf)
                acc[cf] = __builtin_amdgcn_mfma_f32_16x16x32_bf16(a, B[c][cf], acc[cf], 0, 0, 0);
        }
#pragma unroll
        for (int cf = 0; cf < 8; ++cf)
            acc[cf] = __builtin_amdgcn_mfma_f32_16x16x32_bf16(a9, B[9][cf], acc[cf], 0, 0, 0);

        // bf16 main output + fp8 bytes into LDS staging
#pragma unroll
        for (int cf = 0; cf < 8; ++cf)
#pragma unroll
            for (int j = 0; j < 4; ++j) {
                int lr = w * 16 + kg * 4 + j;
                int grow = tile * 64 + lr;
                int gcol = cf * 16 + hl;
                if (grow < NN)
                    news[(long long)grow * DD + gcol] = f2bf(acc[cf][j]);
                int p = __builtin_amdgcn_cvt_pk_fp8_f32(acc[cf][j], 0.f, 0, false);
                f8s[lr * DD + gcol] = (uchar_t)(p & 0xFF);
            }
        __syncthreads();
        // coalesced fp8 copy: 32 B per thread
        {
            int r = tid >> 2, boff = (tid & 3) * 32;
            int grow = tile * 64 + r;
            if (grow < NN) {
                const uint4* s = (const uint4*)&f8s[r * DD + boff];
                uint4* d = (uint4*)&nf8[(long long)grow * DD + boff];
                d[0] = s[0];
                d[1] = s[1];
            }
        }
        __syncthreads();
    }
}

// ------- fused bucket aggregate + GNN GEMM + epilogue (512 threads) ---------
// Phase A: 64-dst LDS CSR + fp8 register gather (128B rows, half the bytes);
// agg rows in LDS (bf16, chunk-XOR swizzle). Phase B: 8 waves = 4 row-groups
// x 2 cf-halves MFMA + residual (bf16 news). xx output bf16.
__global__ __launch_bounds__(512) void k_baggnn(const unsigned* __restrict__ gcur,
                                                const unsigned* __restrict__ pairs,
                                                const uchar_t* __restrict__ nf8,
                                                const ushort_t* __restrict__ news,
                                                const ushort_t* __restrict__ wtF,
                                                ushort_t* __restrict__ xxb) {
    __shared__ unsigned srcs[SLOT];
    __shared__ unsigned hist[64], base[64], cur[64];
    __shared__ ushort_t aggs[64 * DD];         // 16 KB, swizzled 16B chunks
    const int tid = threadIdx.x;
    const int b = blockIdx.x;
    int cnt = (int)gcur[b];
    if (cnt > SLOT) cnt = SLOT;

    if (tid < 64) hist[tid] = 0;
    __syncthreads();
    for (int i = tid; i < cnt; i += 512)
        atomicAdd(&hist[pairs[b * SLOT + i] & 63u], 1u);
    __syncthreads();

    // single-wave exclusive scan of 64 bins
    if (tid < 64) {
        unsigned h = hist[tid], v = h;
#pragma unroll
        for (int off = 1; off < 64; off <<= 1) {
            unsigned n = __shfl_up(v, off);
            if (tid >= off) v += n;
        }
        base[tid] = v - h;
        cur[tid]  = v - h;
    }
    __syncthreads();

    for (int i = tid; i < cnt; i += 512) {
        unsigned v = pairs[b * SLOT + i];
        srcs[atomicAdd(&cur[v & 63u], 1u)] = v >> 6;
    }
    __syncthreads();

    // ---- phase A: wave per dst (8 waves), 4 edge slots x 16 chunk lanes,
    //      8B fp8 per lane, depth-2 pipeline ----
    const int w = tid >> 6, lane = tid & 63;
    const int e = lane >> 4, l = lane & 15;
    for (int d = w; d < 64; d += 8) {
        int gd = b * 64 + d;
        if (gd >= NN) break;                 // uniform per wave
        int s0 = (int)base[d], c = (int)hist[d];
        float acc[8];
#pragma unroll
        for (int j = 0; j < 8; ++j) acc[j] = 0.f;

        uint2 v = make_uint2(0u, 0u);
        if (e < c)
            v = *(const uint2*)&nf8[(long long)srcs[s0 + e] * DD + l * 8];
        for (int i = 4; i < c; i += 4) {
            uint2 vn = make_uint2(0u, 0u);
            int ii = i + e;
            if (ii < c)
                vn = *(const uint2*)&nf8[(long long)srcs[s0 + ii] * DD + l * 8];
            v2f d0 = __builtin_amdgcn_cvt_pk_f32_fp8((int)v.x, false);
            v2f d1 = __builtin_amdgcn_cvt_pk_f32_fp8((int)v.x, true);
            acc[0] += d0[0]; acc[1] += d0[1]; acc[2] += d1[0]; acc[3] += d1[1];
            d0 = __builtin_amdgcn_cvt_pk_f32_fp8((int)v.y, false);
            d1 = __builtin_amdgcn_cvt_pk_f32_fp8((int)v.y, true);
            acc[4] += d0[0]; acc[5] += d0[1]; acc[6] += d1[0]; acc[7] += d1[1];
            v = vn;
        }
        {
            v2f d0 = __builtin_amdgcn_cvt_pk_f32_fp8((int)v.x, false);
            v2f d1 = __builtin_amdgcn_cvt_pk_f32_fp8((int)v.x, true);
            acc[0] += d0[0]; acc[1] += d0[1]; acc[2] += d1[0]; acc[3] += d1[1];
            d0 = __builtin_amdgcn_cvt_pk_f32_fp8((int)v.y, false);
            d1 = __builtin_amdgcn_cvt_pk_f32_fp8((int)v.y, true);
            acc[4] += d0[0]; acc[5] += d0[1]; acc[6] += d1[0]; acc[7] += d1[1];
        }

#pragma unroll
        for (int j = 0; j < 8; ++j) {
            acc[j] += __shfl_xor(acc[j], 16);
            acc[j] += __shfl_xor(acc[j], 32);
        }
        if (e == 0) {
            uint4 o;
            o.x = (unsigned)f2bf(acc[0]) | ((unsigned)f2bf(acc[1]) << 16);
            o.y = (unsigned)f2bf(acc[2]) | ((unsigned)f2bf(acc[3]) << 16);
            o.z = (unsigned)f2bf(acc[4]) | ((unsigned)f2bf(acc[5]) << 16);
            o.w = (unsigned)f2bf(acc[6]) | ((unsigned)f2bf(acc[7]) << 16);
            *(uint4*)&aggs[d * DD + (l ^ (d & 15)) * 8] = o;   // swizzled chunk
        }
    }
    __syncthreads();

    // ---- phase B: gnn MFMA; wave w -> rows (w&3)*16, cf half (w>>2)*4 ----
    const int hl = lane & 15, kg = lane >> 4;
    const int rw = (w & 3) * 16;
    const int cfb = (w >> 2) * 4;
    U4B a[4];
#pragma unroll
    for (int ks = 0; ks < 4; ++ks)
        a[ks].u = *(const uint4*)&aggs[(rw + hl) * DD + ((ks * 4 + kg) ^ hl) * 8];

    f32x4 acc[4];
#pragma unroll
    for (int j = 0; j < 4; ++j) acc[j] = (f32x4)0.f;

#pragma unroll
    for (int ks = 0; ks < 4; ++ks) {
        const ushort_t* bp = &wtF[(ks * 8 + cfb) * 512 + lane * 8];
#pragma unroll
        for (int cf = 0; cf < 4; ++cf) {
            bf16x8 bfr = *(const bf16x8*)&bp[cf * 512];
            acc[cf] = __builtin_amdgcn_mfma_f32_16x16x32_bf16(a[ks].b, bfr, acc[cf], 0, 0, 0);
        }
    }

#pragma unroll
    for (int j = 0; j < 4; ++j) {
        int lr = rw + kg * 4 + j;
        int grow = b * 64 + lr;
        if (grow < NN) {
            float s = 1.f / fmaxf((float)hist[lr], 1.f);
#pragma unroll
            for (int cf = 0; cf < 4; ++cf) {
                int gcol = (cfb + cf) * 16 + hl;
                float nv = bf2f((unsigned)news[(long long)grow * DD + gcol]);
                xxb[(long long)grow * DD + gcol] = f2bf(nv + acc[cf][j] * s);
            }
        }
    }
}

// ---------------- fused user vector + scores (bf16 xx gathers) --------------
__global__ __launch_bounds__(128) void k_user(const int* __restrict__ hist,
                                              const int* __restrict__ cand,
                                              const ushort_t* __restrict__ xxb,
                                              float* __restrict__ out) {
    __shared__ float part[2][128];
    __shared__ float cnts[2];
    __shared__ float uvs[128];
    const int b = blockIdx.x, t = threadIdx.x;
    const int w = t >> 6, lane = t & 63;

    float s0 = 0.f, s1 = 0.f, cnt = 0.f;
    for (int h = w; h < HL; h += 2) {
        int id = hist[b * HL + h];
        if (id != 0) {
            unsigned v = *(const unsigned*)&xxb[(long long)id * DD + lane * 2];
            s0 += bf2f(v & 0xFFFFu);
            s1 += bf2f(v >> 16);
            cnt += 1.f;
        }
    }
    part[w][lane * 2]     = s0;
    part[w][lane * 2 + 1] = s1;
    if (lane == 0) cnts[w] = cnt;
    __syncthreads();

    float inv = 1.f / fmaxf(cnts[0] + cnts[1], 1e-9f);
    uvs[t] = (part[0][t] + part[1][t]) * inv;
    __syncthreads();

    float2 uvp = *(const float2*)&uvs[lane * 2];
    for (int c = w; c < CL; c += 2) {
        int id = cand[b * CL + c];
        unsigned v = *(const unsigned*)&xxb[(long long)id * DD + lane * 2];
        float p = uvp.x * bf2f(v & 0xFFFFu) + uvp.y * bf2f(v >> 16);
#pragma unroll
        for (int off = 32; off >= 1; off >>= 1) p += __shfl_xor(p, off);
        if (lane == 0) out[b * CL + c] = p;
    }
}

extern "C" void kernel_launch(void* const* d_in, const int* in_sizes, int n_in,
                              void* d_out, int out_size, void* d_ws, size_t ws_size,
                              hipStream_t stream) {
    const float* x    = (const float*)d_in[0];
    // d_in[1] = n_id == arange(N) -> identity scatter, unused
    const int*   ei   = (const int*)d_in[2];
    const int*   hist = (const int*)d_in[3];
    const int*   cand = (const int*)d_in[4];
    const float* Wenc = (const float*)d_in[5];
    const float* Wgnn = (const float*)d_in[6];
    float* out = (float*)d_out;

    ushort_t* news_bf = (ushort_t*)d_ws;                   // [NN*DD] bf16
    ushort_t* xx_bf   = news_bf + (size_t)NN * DD;         // [NN*DD] bf16
    ushort_t* wt_enc  = xx_bf + (size_t)NN * DD;           // [WTE_N]
    ushort_t* wt_gnn  = wt_enc + WTE_N;                    // [WTG_N]
    uchar_t*  news_f8 = (uchar_t*)(wt_gnn + WTG_N);        // [NN*DD] fp8
    unsigned* gcur    = (unsigned*)(news_f8 + (size_t)NN * DD); // [NBUCK]
    unsigned* pairs   = gcur + NBUCK;                      // [NBUCK*SLOT]

    hipMemsetAsync(gcur, 0, NBUCK * sizeof(unsigned), stream);

    k_prep<<<PBLK + PREPB, 256, 0, stream>>>(ei, gcur, pairs, Wenc, Wgnn, wt_enc, wt_gnn);
    enc_mfma<<<256, 256, 0, stream>>>(x, wt_enc, news_bf, news_f8);
    k_baggnn<<<NBUCK, 512, 0, stream>>>(gcur, pairs, news_f8, news_bf, wt_gnn, xx_bf);
    k_user<<<NB, 128, 0, stream>>>(hist, cand, xx_bf, out);
}